// Round 7
// baseline (395.981 us; speedup 1.0000x reference)
//
#include <hip/hip_runtime.h>
#include <hip/hip_fp16.h>
#include <math.h>

static constexpr int NN = 100000;   // nodes
static constexpr int NE = 1600000;  // edges
static constexpr int BUCK_SH = 5;   // 32 nodes per bucket
static constexpr int NBUK = NN >> BUCK_SH;   // 3125 (exact)
static constexpr int NCH = 64;               // chunks (one scat block each)
static constexpr int CH = NE / NCH;          // 25000 edges per chunk (exact)
static constexpr int SUB = 4;                // hist sub-blocks per chunk
static constexpr int SUBE = CH / SUB;        // 6250 edges per hist block

__global__ void k_zero(int* __restrict__ p, int n) {
  int i = blockIdx.x * blockDim.x + threadIdx.x;
  if (i < n) p[i] = 0;
}

// pass 1: per-chunk bucket histogram H[chunk][bucket], LDS-staged
__global__ __launch_bounds__(256)
void k_chist(const int* __restrict__ ei, int* __restrict__ H) {
  __shared__ int h[NBUK];
  for (int i = threadIdx.x; i < NBUK; i += 256) h[i] = 0;
  __syncthreads();
  int chunk = blockIdx.x / SUB, sub = blockIdx.x % SUB;
  int start = chunk * CH + sub * SUBE;
  for (int e = start + threadIdx.x; e < start + SUBE; e += 256)
    atomicAdd(&h[ei[NE + e] >> BUCK_SH], 1);
  __syncthreads();
  int* Hc = H + chunk * NBUK;
  for (int i = threadIdx.x; i < NBUK; i += 256) {
    int v = h[i];
    if (v) atomicAdd(&Hc[i], v);
  }
}

// pass 2: in-place exclusive prefix over chunks per bucket; totals -> tot
__global__ void k_csum(int* __restrict__ H, int* __restrict__ tot) {
  int b = blockIdx.x * blockDim.x + threadIdx.x;
  if (b >= NBUK) return;
  int acc = 0;
#pragma unroll 4
  for (int c = 0; c < NCH; ++c) {
    int v = H[c * NBUK + b];
    H[c * NBUK + b] = acc;
    acc += v;
  }
  tot[b] = acc;
}

// single-block scan of bucket totals -> boff (exclusive), boff[NBUK]=NE
__global__ __launch_bounds__(1024)
void k_bscan(const int* __restrict__ tot, int* __restrict__ boff) {
  __shared__ int buf[1024];
  __shared__ int s_carry;
  int tid = threadIdx.x;
  if (tid == 0) s_carry = 0;
  __syncthreads();
  for (int base = 0; base < NBUK; base += 1024) {
    int i = base + tid;
    int v = (i < NBUK) ? tot[i] : 0;
    buf[tid] = v;
    __syncthreads();
#pragma unroll
    for (int off = 1; off < 1024; off <<= 1) {
      int t = (tid >= off) ? buf[tid - off] : 0;
      __syncthreads();
      buf[tid] += t;
      __syncthreads();
    }
    int excl = buf[tid] - v;
    int carry = s_carry;
    if (i < NBUK) boff[i] = carry + excl;
    __syncthreads();
    if (tid == 1023) s_carry = carry + buf[1023];
    __syncthreads();
  }
  if (tid == 0) boff[NBUK] = s_carry;   // == NE
}

// pass 3: one block per chunk; LDS cursors; write packed (dstLow5,src) u32
__global__ __launch_bounds__(1024)
void k_scat(const int* __restrict__ ei, const int* __restrict__ H,
            const int* __restrict__ boff, unsigned* __restrict__ se) {
  __shared__ int cur[NBUK];
  int chunk = blockIdx.x;
  const int* Hc = H + chunk * NBUK;
  for (int i = threadIdx.x; i < NBUK; i += 1024) cur[i] = boff[i] + Hc[i];
  __syncthreads();
  int start = chunk * CH;
  for (int e = start + threadIdx.x; e < start + CH; e += 1024) {
    int src = ei[e], dst = ei[NE + e];
    int pos = atomicAdd(&cur[dst >> BUCK_SH], 1);
    se[pos] = ((unsigned)(dst & 31) << 20) | (unsigned)src;   // src < 2^17
  }
}

// one block per bucket: local counting sort -> rowptr, dis, csr_src
__global__ __launch_bounds__(256)
void k_blocal(const unsigned* __restrict__ se, const int* __restrict__ boff,
              int* __restrict__ rowptr, float* __restrict__ dis, int* __restrict__ csr_src) {
  int b = blockIdx.x;
  int base = boff[b], end = boff[b + 1];
  __shared__ int cnt[32], off[32];
  int tid = threadIdx.x;
  if (tid < 32) cnt[tid] = 0;
  __syncthreads();
  for (int k = base + tid; k < end; k += 256)
    atomicAdd(&cnt[se[k] >> 20], 1);
  __syncthreads();
  if (tid == 0) {
    int acc = 0;
#pragma unroll
    for (int i = 0; i < 32; ++i) { off[i] = acc; acc += cnt[i]; }
  }
  __syncthreads();
  if (tid < 32) {
    int node = (b << BUCK_SH) + tid;
    rowptr[node] = base + off[tid];
    dis[node] = rsqrtf(1.0f + (float)cnt[tid]);
    cnt[tid] = 0;                       // reuse as cursor
  }
  if (b == 0 && tid == 64) rowptr[NN] = NE;
  __syncthreads();
  for (int k = base + tid; k < end; k += 256) {
    unsigned e = se[k];
    int dl = e >> 20;
    int pos = base + off[dl] + atomicAdd(&cnt[dl], 1);
    csr_src[pos] = (int)(e & 0xFFFFFu);
  }
}

// g[row][c] = (sum_k in[row][k] * W[k][c]) * dis[row]   (fp16 output)
// Persistent-style: stage W once per block, grid-stride rows, RT rows/thread.
template<int K, int C, int RT>
__global__ __launch_bounds__(256)
void k_gemm_scale_h(const float* __restrict__ in, const float* __restrict__ W,
                    const float* __restrict__ dis, __half* __restrict__ g) {
  __shared__ float Ws[K * C];
  for (int t = threadIdx.x * 4; t < K * C; t += 1024)
    *(float4*)&Ws[t] = *(const float4*)&W[t];
  __syncthreads();
  constexpr int RW = 256 / C;      // row-groups per pass
  constexpr int R = RW * RT;       // rows per block iteration
  int rl = threadIdx.x / C, c = threadIdx.x % C;
  for (int row0 = blockIdx.x * R; row0 < NN; row0 += gridDim.x * R) {
    float acc[RT];
    const float* inr[RT];
    bool valid[RT];
#pragma unroll
    for (int r = 0; r < RT; ++r) {
      int row = row0 + rl + r * RW;
      valid[r] = row < NN;
      inr[r] = in + (size_t)(valid[r] ? row : 0) * K;
      acc[r] = 0.f;
    }
#pragma unroll
    for (int kc = 0; kc < K; kc += 4) {
      float4 v[RT];
#pragma unroll
      for (int r = 0; r < RT; ++r) v[r] = *(const float4*)&inr[r][kc];
#pragma unroll
      for (int j = 0; j < 4; ++j) {
        float w = Ws[(kc + j) * C + c];
#pragma unroll
        for (int r = 0; r < RT; ++r) acc[r] += (&v[r].x)[j] * w;
      }
    }
#pragma unroll
    for (int r = 0; r < RT; ++r) {
      int row = row0 + rl + r * RW;
      if (valid[r]) g[row * C + c] = __float2half(acc[r] * dis[row]);
    }
  }
}

// fp32 variant for the tiny last layer
template<int K, int C>
__global__ void k_gemm_scale(const float* __restrict__ in, const float* __restrict__ W,
                             const float* __restrict__ dis, float* __restrict__ g) {
  __shared__ float Ws[K * C];
  for (int t = threadIdx.x; t < K * C; t += blockDim.x) Ws[t] = W[t];
  __syncthreads();
  constexpr int R = 256 / (C > 256 ? 256 : C);
  int t = threadIdx.x;
  int rl = t / C, c = t % C;
  int row = blockIdx.x * R + rl;
  if (row >= NN) return;
  const float* inr = in + row * K;
  float acc = 0.f;
#pragma unroll
  for (int k = 0; k < K; ++k) acc += inr[k] * Ws[k * C + c];
  g[row * C + c] = acc * dis[row];
}

// CSR gather-aggregate, fp16 messages, 4-deep unrolled for MLP.
template<bool TANH>
__global__ void k_agg64h(const int* __restrict__ rowptr, const int* __restrict__ csr_src,
                         const __half* __restrict__ g, const float* __restrict__ dis,
                         const float* __restrict__ b, float* __restrict__ out) {
  int node = blockIdx.x * 4 + (threadIdx.x >> 6);
  int lane = threadIdx.x & 63;
  if (node >= NN) return;
  float a0 = __half2float(g[node * 64 + lane]);   // self loop
  float a1 = 0.f, a2 = 0.f, a3 = 0.f;
  int beg = rowptr[node], end = rowptr[node + 1];
  int k = beg;
  for (; k + 4 <= end; k += 4) {
    int s0 = csr_src[k], s1 = csr_src[k + 1], s2 = csr_src[k + 2], s3 = csr_src[k + 3];
    float m0 = __half2float(g[s0 * 64 + lane]);
    float m1 = __half2float(g[s1 * 64 + lane]);
    float m2 = __half2float(g[s2 * 64 + lane]);
    float m3 = __half2float(g[s3 * 64 + lane]);
    a0 += m0; a1 += m1; a2 += m2; a3 += m3;
  }
  for (; k < end; ++k) a0 += __half2float(g[csr_src[k] * 64 + lane]);
  float v = ((a0 + a1) + (a2 + a3)) * dis[node] + b[lane];
  out[node * 64 + lane] = TANH ? tanhf(v) : v;
}

template<bool TANH>
__global__ void k_agg32h(const int* __restrict__ rowptr, const int* __restrict__ csr_src,
                         const __half* __restrict__ g, const float* __restrict__ dis,
                         const float* __restrict__ b, float* __restrict__ out) {
  int node = blockIdx.x * 8 + (threadIdx.x >> 5);
  int lane = threadIdx.x & 31;
  if (node >= NN) return;
  float a0 = __half2float(g[node * 32 + lane]);
  float a1 = 0.f, a2 = 0.f, a3 = 0.f;
  int beg = rowptr[node], end = rowptr[node + 1];
  int k = beg;
  for (; k + 4 <= end; k += 4) {
    int s0 = csr_src[k], s1 = csr_src[k + 1], s2 = csr_src[k + 2], s3 = csr_src[k + 3];
    float m0 = __half2float(g[s0 * 32 + lane]);
    float m1 = __half2float(g[s1 * 32 + lane]);
    float m2 = __half2float(g[s2 * 32 + lane]);
    float m3 = __half2float(g[s3 * 32 + lane]);
    a0 += m0; a1 += m1; a2 += m2; a3 += m3;
  }
  for (; k < end; ++k) a0 += __half2float(g[csr_src[k] * 32 + lane]);
  float v = ((a0 + a1) + (a2 + a3)) * dis[node] + b[lane];
  out[node * 32 + lane] = TANH ? tanhf(v) : v;
}

__global__ void k_agg1(const int* __restrict__ rowptr, const int* __restrict__ csr_src,
                       const float* __restrict__ g, const float* __restrict__ dis,
                       const float* __restrict__ b, float* __restrict__ out) {
  int node = blockIdx.x * blockDim.x + threadIdx.x;
  if (node >= NN) return;
  float a0 = g[node], a1 = 0.f, a2 = 0.f, a3 = 0.f;
  int beg = rowptr[node], end = rowptr[node + 1];
  int k = beg;
  for (; k + 4 <= end; k += 4) {
    float m0 = g[csr_src[k]], m1 = g[csr_src[k + 1]];
    float m2 = g[csr_src[k + 2]], m3 = g[csr_src[k + 3]];
    a0 += m0; a1 += m1; a2 += m2; a3 += m3;
  }
  for (; k < end; ++k) a0 += g[csr_src[k]];
  out[node] = ((a0 + a1) + (a2 + a3)) * dis[node] + b[0];
}

extern "C" void kernel_launch(void* const* d_in, const int* in_sizes, int n_in,
                              void* d_out, int out_size, void* d_ws, size_t ws_size,
                              hipStream_t stream) {
  const float* x  = (const float*)d_in[0];
  const int*   ei = (const int*)d_in[1];
  const float* W1 = (const float*)d_in[2];
  const float* b1 = (const float*)d_in[3];
  const float* W2 = (const float*)d_in[4];
  const float* b2 = (const float*)d_in[5];
  const float* W3 = (const float*)d_in[6];
  const float* b3 = (const float*)d_in[7];
  float* out = (float*)d_out;

  char* ws = (char*)d_ws;
  int*      H       = (int*)ws;      ws += (size_t)NCH * NBUK * 4;          // 800 KB
  int*      tot     = (int*)ws;      ws += ((NBUK + 255)/256)*256 * 4;
  int*      boff    = (int*)ws;      ws += ((NBUK + 1 + 255)/256)*256 * 4;
  unsigned* se      = (unsigned*)ws; ws += (size_t)NE * 4;                  // 6.4 MB
  int*      rowptr  = (int*)ws;      ws += ((NN + 1 + 255)/256)*256 * 4;
  int*      csr_src = (int*)ws;      ws += (size_t)NE * 4;                  // 6.4 MB
  float*    dis     = (float*)ws;    ws += ((NN + 255)/256)*256 * 4;
  __half*   Ah      = (__half*)ws;   ws += (size_t)NN * 64 * 2;             // 12.8 MB
  float*    Af      = (float*)ws;    ws += (size_t)NN * 4;
  float*    B       = (float*)ws;    // fp32 h buffer (N*64), 25.6 MB

  // ---- CSR build (deterministic two-pass counting sort) + dis
  k_zero  <<<(NCH * NBUK + 255) / 256, 256, 0, stream>>>(H, NCH * NBUK);
  k_chist <<<NCH * SUB, 256, 0, stream>>>(ei, H);
  k_csum  <<<(NBUK + 255) / 256, 256, 0, stream>>>(H, tot);
  k_bscan <<<1, 1024, 0, stream>>>(tot, boff);
  k_scat  <<<NCH, 1024, 0, stream>>>(ei, H, boff, se);
  k_blocal<<<NBUK, 256, 0, stream>>>(se, boff, rowptr, dis, csr_src);

  // ---- layer 1: 64 -> 64, tanh
  k_gemm_scale_h<64, 64, 4><<<1024, 256, 0, stream>>>(x, W1, dis, Ah);
  k_agg64h<true><<<(NN + 3) / 4, 256, 0, stream>>>(rowptr, csr_src, Ah, dis, b1, B);

  // ---- layer 2: 64 -> 32, tanh
  k_gemm_scale_h<64, 32, 4><<<1024, 256, 0, stream>>>(B, W2, dis, Ah);
  k_agg32h<true><<<(NN + 7) / 8, 256, 0, stream>>>(rowptr, csr_src, Ah, dis, b2, B);

  // ---- layer 3: 32 -> 1 (no activation) -> d_out
  k_gemm_scale<32, 1><<<(NN + 255) / 256, 256, 0, stream>>>(B, W3, dis, Af);
  k_agg1<<<(NN + 255) / 256, 256, 0, stream>>>(rowptr, csr_src, Af, dis, b3, out);
}

// Round 8
// 350.038 us; speedup vs baseline: 1.1313x; 1.1313x over previous
//
#include <hip/hip_runtime.h>
#include <hip/hip_fp16.h>
#include <math.h>

static constexpr int NN = 100000;   // nodes
static constexpr int NE = 1600000;  // edges
static constexpr int BUCK_SH = 5;   // 32 nodes per bucket
static constexpr int NBUK = NN >> BUCK_SH;   // 3125 (exact)
static constexpr int NCH = 64;               // chunks (one scat block each)
static constexpr int CH = NE / NCH;          // 25000 edges per chunk (exact)
static constexpr int SUB = 4;                // hist sub-blocks per chunk
static constexpr int SUBE = CH / SUB;        // 6250 edges per hist block

__global__ void k_zero(int* __restrict__ p, int n) {
  int i = blockIdx.x * blockDim.x + threadIdx.x;
  if (i < n) p[i] = 0;
}

// pass 1: per-chunk bucket histogram H[chunk][bucket], LDS-staged
__global__ __launch_bounds__(256)
void k_chist(const int* __restrict__ ei, int* __restrict__ H) {
  __shared__ int h[NBUK];
  for (int i = threadIdx.x; i < NBUK; i += 256) h[i] = 0;
  __syncthreads();
  int chunk = blockIdx.x / SUB, sub = blockIdx.x % SUB;
  int start = chunk * CH + sub * SUBE;
  for (int e = start + threadIdx.x; e < start + SUBE; e += 256)
    atomicAdd(&h[ei[NE + e] >> BUCK_SH], 1);
  __syncthreads();
  int* Hc = H + chunk * NBUK;
  for (int i = threadIdx.x; i < NBUK; i += 256) {
    int v = h[i];
    if (v) atomicAdd(&Hc[i], v);
  }
}

// pass 2: in-place exclusive prefix over chunks per bucket; totals -> tot
__global__ void k_csum(int* __restrict__ H, int* __restrict__ tot) {
  int b = blockIdx.x * blockDim.x + threadIdx.x;
  if (b >= NBUK) return;
  int acc = 0;
#pragma unroll 4
  for (int c = 0; c < NCH; ++c) {
    int v = H[c * NBUK + b];
    H[c * NBUK + b] = acc;
    acc += v;
  }
  tot[b] = acc;
}

// single-block scan of bucket totals -> boff (exclusive), boff[NBUK]=NE
__global__ __launch_bounds__(1024)
void k_bscan(const int* __restrict__ tot, int* __restrict__ boff) {
  __shared__ int buf[1024];
  __shared__ int s_carry;
  int tid = threadIdx.x;
  if (tid == 0) s_carry = 0;
  __syncthreads();
  for (int base = 0; base < NBUK; base += 1024) {
    int i = base + tid;
    int v = (i < NBUK) ? tot[i] : 0;
    buf[tid] = v;
    __syncthreads();
#pragma unroll
    for (int off = 1; off < 1024; off <<= 1) {
      int t = (tid >= off) ? buf[tid - off] : 0;
      __syncthreads();
      buf[tid] += t;
      __syncthreads();
    }
    int excl = buf[tid] - v;
    int carry = s_carry;
    if (i < NBUK) boff[i] = carry + excl;
    __syncthreads();
    if (tid == 1023) s_carry = carry + buf[1023];
    __syncthreads();
  }
  if (tid == 0) boff[NBUK] = s_carry;   // == NE
}

// pass 3: one block per chunk; LDS cursors; write packed (dstLow5,src) u32
__global__ __launch_bounds__(1024)
void k_scat(const int* __restrict__ ei, const int* __restrict__ H,
            const int* __restrict__ boff, unsigned* __restrict__ se) {
  __shared__ int cur[NBUK];
  int chunk = blockIdx.x;
  const int* Hc = H + chunk * NBUK;
  for (int i = threadIdx.x; i < NBUK; i += 1024) cur[i] = boff[i] + Hc[i];
  __syncthreads();
  int start = chunk * CH;
  for (int e = start + threadIdx.x; e < start + CH; e += 1024) {
    int src = ei[e], dst = ei[NE + e];
    int pos = atomicAdd(&cur[dst >> BUCK_SH], 1);
    se[pos] = ((unsigned)(dst & 31) << 20) | (unsigned)src;   // src < 2^17
  }
}

// one block per bucket: local counting sort -> rowptr, dis, csr_src
__global__ __launch_bounds__(256)
void k_blocal(const unsigned* __restrict__ se, const int* __restrict__ boff,
              int* __restrict__ rowptr, float* __restrict__ dis, int* __restrict__ csr_src) {
  int b = blockIdx.x;
  int base = boff[b], end = boff[b + 1];
  __shared__ int cnt[32], off[32];
  int tid = threadIdx.x;
  if (tid < 32) cnt[tid] = 0;
  __syncthreads();
  for (int k = base + tid; k < end; k += 256)
    atomicAdd(&cnt[se[k] >> 20], 1);
  __syncthreads();
  if (tid == 0) {
    int acc = 0;
#pragma unroll
    for (int i = 0; i < 32; ++i) { off[i] = acc; acc += cnt[i]; }
  }
  __syncthreads();
  if (tid < 32) {
    int node = (b << BUCK_SH) + tid;
    rowptr[node] = base + off[tid];
    dis[node] = rsqrtf(1.0f + (float)cnt[tid]);
    cnt[tid] = 0;                       // reuse as cursor
  }
  if (b == 0 && tid == 64) rowptr[NN] = NE;
  __syncthreads();
  for (int k = base + tid; k < end; k += 256) {
    unsigned e = se[k];
    int dl = e >> 20;
    int pos = base + off[dl] + atomicAdd(&cnt[dl], 1);
    csr_src[pos] = (int)(e & 0xFFFFFu);
  }
}

// GEMM 64->64, fp16 out, W-column in registers, no LDS.
// One wave per row; lane = output column. Wave-uniform float4 row loads.
__global__ __launch_bounds__(256)
void k_gemm64_h(const float* __restrict__ in, const float* __restrict__ W,
                const float* __restrict__ dis, __half* __restrict__ g) {
  int c = threadIdx.x & 63;
  int wid = threadIdx.x >> 6;          // 4 waves/block
  float Wc[64];
#pragma unroll
  for (int k = 0; k < 64; ++k) Wc[k] = W[k * 64 + c];
  int nw = gridDim.x * 4;
  for (int row = blockIdx.x * 4 + wid; row < NN; row += nw) {
    const float* rp = in + (size_t)row * 64;
    float acc = 0.f;
#pragma unroll
    for (int kc = 0; kc < 64; kc += 4) {
      float4 v = *(const float4*)(rp + kc);
      acc = fmaf(v.x, Wc[kc + 0], acc);
      acc = fmaf(v.y, Wc[kc + 1], acc);
      acc = fmaf(v.z, Wc[kc + 2], acc);
      acc = fmaf(v.w, Wc[kc + 3], acc);
    }
    g[row * 64 + c] = __float2half(acc * dis[row]);
  }
}

// GEMM 64->32, fp16 out. One wave per row; lane&31 = column, lane>>5 = K-half.
// Halves combined with shfl_down(32).
__global__ __launch_bounds__(256)
void k_gemm32_h(const float* __restrict__ in, const float* __restrict__ W,
                const float* __restrict__ dis, __half* __restrict__ g) {
  int lane = threadIdx.x & 63;
  int c = lane & 31;
  int ksub = lane >> 5;                // 0 or 1
  int wid = threadIdx.x >> 6;
  float Wc[32];
#pragma unroll
  for (int k = 0; k < 32; ++k) Wc[k] = W[(ksub * 32 + k) * 32 + c];
  int nw = gridDim.x * 4;
  for (int row = blockIdx.x * 4 + wid; row < NN; row += nw) {
    const float* rp = in + (size_t)row * 64 + ksub * 32;
    float acc = 0.f;
#pragma unroll
    for (int kc = 0; kc < 32; kc += 4) {
      float4 v = *(const float4*)(rp + kc);
      acc = fmaf(v.x, Wc[kc + 0], acc);
      acc = fmaf(v.y, Wc[kc + 1], acc);
      acc = fmaf(v.z, Wc[kc + 2], acc);
      acc = fmaf(v.w, Wc[kc + 3], acc);
    }
    acc += __shfl_down(acc, 32);       // combine K-halves
    if (ksub == 0) g[row * 32 + c] = __float2half(acc * dis[row]);
  }
}

// fp32 GEMM for the tiny last layer (32 -> 1)
template<int K, int C>
__global__ void k_gemm_scale(const float* __restrict__ in, const float* __restrict__ W,
                             const float* __restrict__ dis, float* __restrict__ g) {
  __shared__ float Ws[K * C];
  for (int t = threadIdx.x; t < K * C; t += blockDim.x) Ws[t] = W[t];
  __syncthreads();
  constexpr int R = 256 / (C > 256 ? 256 : C);
  int t = threadIdx.x;
  int rl = t / C, c = t % C;
  int row = blockIdx.x * R + rl;
  if (row >= NN) return;
  const float* inr = in + row * K;
  float acc = 0.f;
#pragma unroll
  for (int k = 0; k < K; ++k) acc += inr[k] * Ws[k * C + c];
  g[row * C + c] = acc * dis[row];
}

// CSR gather-aggregate, fp16 messages, 4-deep unrolled for MLP.
template<bool TANH>
__global__ void k_agg64h(const int* __restrict__ rowptr, const int* __restrict__ csr_src,
                         const __half* __restrict__ g, const float* __restrict__ dis,
                         const float* __restrict__ b, float* __restrict__ out) {
  int node = blockIdx.x * 4 + (threadIdx.x >> 6);
  int lane = threadIdx.x & 63;
  if (node >= NN) return;
  float a0 = __half2float(g[node * 64 + lane]);   // self loop
  float a1 = 0.f, a2 = 0.f, a3 = 0.f;
  int beg = rowptr[node], end = rowptr[node + 1];
  int k = beg;
  for (; k + 4 <= end; k += 4) {
    int s0 = csr_src[k], s1 = csr_src[k + 1], s2 = csr_src[k + 2], s3 = csr_src[k + 3];
    float m0 = __half2float(g[s0 * 64 + lane]);
    float m1 = __half2float(g[s1 * 64 + lane]);
    float m2 = __half2float(g[s2 * 64 + lane]);
    float m3 = __half2float(g[s3 * 64 + lane]);
    a0 += m0; a1 += m1; a2 += m2; a3 += m3;
  }
  for (; k < end; ++k) a0 += __half2float(g[csr_src[k] * 64 + lane]);
  float v = ((a0 + a1) + (a2 + a3)) * dis[node] + b[lane];
  out[node * 64 + lane] = TANH ? tanhf(v) : v;
}

template<bool TANH>
__global__ void k_agg32h(const int* __restrict__ rowptr, const int* __restrict__ csr_src,
                         const __half* __restrict__ g, const float* __restrict__ dis,
                         const float* __restrict__ b, float* __restrict__ out) {
  int node = blockIdx.x * 8 + (threadIdx.x >> 5);
  int lane = threadIdx.x & 31;
  if (node >= NN) return;
  float a0 = __half2float(g[node * 32 + lane]);
  float a1 = 0.f, a2 = 0.f, a3 = 0.f;
  int beg = rowptr[node], end = rowptr[node + 1];
  int k = beg;
  for (; k + 4 <= end; k += 4) {
    int s0 = csr_src[k], s1 = csr_src[k + 1], s2 = csr_src[k + 2], s3 = csr_src[k + 3];
    float m0 = __half2float(g[s0 * 32 + lane]);
    float m1 = __half2float(g[s1 * 32 + lane]);
    float m2 = __half2float(g[s2 * 32 + lane]);
    float m3 = __half2float(g[s3 * 32 + lane]);
    a0 += m0; a1 += m1; a2 += m2; a3 += m3;
  }
  for (; k < end; ++k) a0 += __half2float(g[csr_src[k] * 32 + lane]);
  float v = ((a0 + a1) + (a2 + a3)) * dis[node] + b[lane];
  out[node * 32 + lane] = TANH ? tanhf(v) : v;
}

__global__ void k_agg1(const int* __restrict__ rowptr, const int* __restrict__ csr_src,
                       const float* __restrict__ g, const float* __restrict__ dis,
                       const float* __restrict__ b, float* __restrict__ out) {
  int node = blockIdx.x * blockDim.x + threadIdx.x;
  if (node >= NN) return;
  float a0 = g[node], a1 = 0.f, a2 = 0.f, a3 = 0.f;
  int beg = rowptr[node], end = rowptr[node + 1];
  int k = beg;
  for (; k + 4 <= end; k += 4) {
    float m0 = g[csr_src[k]], m1 = g[csr_src[k + 1]];
    float m2 = g[csr_src[k + 2]], m3 = g[csr_src[k + 3]];
    a0 += m0; a1 += m1; a2 += m2; a3 += m3;
  }
  for (; k < end; ++k) a0 += g[csr_src[k]];
  out[node] = ((a0 + a1) + (a2 + a3)) * dis[node] + b[0];
}

extern "C" void kernel_launch(void* const* d_in, const int* in_sizes, int n_in,
                              void* d_out, int out_size, void* d_ws, size_t ws_size,
                              hipStream_t stream) {
  const float* x  = (const float*)d_in[0];
  const int*   ei = (const int*)d_in[1];
  const float* W1 = (const float*)d_in[2];
  const float* b1 = (const float*)d_in[3];
  const float* W2 = (const float*)d_in[4];
  const float* b2 = (const float*)d_in[5];
  const float* W3 = (const float*)d_in[6];
  const float* b3 = (const float*)d_in[7];
  float* out = (float*)d_out;

  char* ws = (char*)d_ws;
  int*      H       = (int*)ws;      ws += (size_t)NCH * NBUK * 4;          // 800 KB
  int*      tot     = (int*)ws;      ws += ((NBUK + 255)/256)*256 * 4;
  int*      boff    = (int*)ws;      ws += ((NBUK + 1 + 255)/256)*256 * 4;
  unsigned* se      = (unsigned*)ws; ws += (size_t)NE * 4;                  // 6.4 MB
  int*      rowptr  = (int*)ws;      ws += ((NN + 1 + 255)/256)*256 * 4;
  int*      csr_src = (int*)ws;      ws += (size_t)NE * 4;                  // 6.4 MB
  float*    dis     = (float*)ws;    ws += ((NN + 255)/256)*256 * 4;
  __half*   Ah      = (__half*)ws;   ws += (size_t)NN * 64 * 2;             // 12.8 MB
  float*    Af      = (float*)ws;    ws += (size_t)NN * 4;
  float*    B       = (float*)ws;    // fp32 h buffer (N*64), 25.6 MB

  // ---- CSR build (deterministic two-pass counting sort) + dis
  k_zero  <<<(NCH * NBUK + 255) / 256, 256, 0, stream>>>(H, NCH * NBUK);
  k_chist <<<NCH * SUB, 256, 0, stream>>>(ei, H);
  k_csum  <<<(NBUK + 255) / 256, 256, 0, stream>>>(H, tot);
  k_bscan <<<1, 1024, 0, stream>>>(tot, boff);
  k_scat  <<<NCH, 1024, 0, stream>>>(ei, H, boff, se);
  k_blocal<<<NBUK, 256, 0, stream>>>(se, boff, rowptr, dis, csr_src);

  // ---- layer 1: 64 -> 64, tanh
  k_gemm64_h<<<1024, 256, 0, stream>>>(x, W1, dis, Ah);
  k_agg64h<true><<<(NN + 3) / 4, 256, 0, stream>>>(rowptr, csr_src, Ah, dis, b1, B);

  // ---- layer 2: 64 -> 32, tanh
  k_gemm32_h<<<1024, 256, 0, stream>>>(B, W2, dis, Ah);
  k_agg32h<true><<<(NN + 7) / 8, 256, 0, stream>>>(rowptr, csr_src, Ah, dis, b2, B);

  // ---- layer 3: 32 -> 1 (no activation) -> d_out
  k_gemm_scale<32, 1><<<(NN + 255) / 256, 256, 0, stream>>>(B, W3, dis, Af);
  k_agg1<<<(NN + 255) / 256, 256, 0, stream>>>(rowptr, csr_src, Af, dis, b3, out);
}

// Round 9
// 348.454 us; speedup vs baseline: 1.1364x; 1.0045x over previous
//
#include <hip/hip_runtime.h>
#include <hip/hip_fp16.h>
#include <math.h>

static constexpr int NN = 100000;   // nodes
static constexpr int NE = 1600000;  // edges
static constexpr int BUCK_SH = 5;   // 32 nodes per bucket
static constexpr int NBUK = NN >> BUCK_SH;   // 3125 (exact)
static constexpr int NCH = 64;               // chunks (one scat block each)
static constexpr int CH = NE / NCH;          // 25000 edges per chunk (exact)
static constexpr int SUB = 4;                // hist sub-blocks per chunk
static constexpr int SUBE = CH / SUB;        // 6250 edges per hist block

__global__ void k_zero(int* __restrict__ p, int n) {
  int i = blockIdx.x * blockDim.x + threadIdx.x;
  if (i < n) p[i] = 0;
}

// pass 1: per-chunk bucket histogram H[chunk][bucket], LDS-staged
__global__ __launch_bounds__(256)
void k_chist(const int* __restrict__ ei, int* __restrict__ H) {
  __shared__ int h[NBUK];
  for (int i = threadIdx.x; i < NBUK; i += 256) h[i] = 0;
  __syncthreads();
  int chunk = blockIdx.x / SUB, sub = blockIdx.x % SUB;
  int start = chunk * CH + sub * SUBE;
  for (int e = start + threadIdx.x; e < start + SUBE; e += 256)
    atomicAdd(&h[ei[NE + e] >> BUCK_SH], 1);
  __syncthreads();
  int* Hc = H + chunk * NBUK;
  for (int i = threadIdx.x; i < NBUK; i += 256) {
    int v = h[i];
    if (v) atomicAdd(&Hc[i], v);
  }
}

// pass 2: in-place exclusive prefix over chunks per bucket; totals -> tot
__global__ void k_csum(int* __restrict__ H, int* __restrict__ tot) {
  int b = blockIdx.x * blockDim.x + threadIdx.x;
  if (b >= NBUK) return;
  int acc = 0;
#pragma unroll 4
  for (int c = 0; c < NCH; ++c) {
    int v = H[c * NBUK + b];
    H[c * NBUK + b] = acc;
    acc += v;
  }
  tot[b] = acc;
}

// single-block scan of bucket totals -> boff (exclusive), boff[NBUK]=NE
__global__ __launch_bounds__(1024)
void k_bscan(const int* __restrict__ tot, int* __restrict__ boff) {
  __shared__ int buf[1024];
  __shared__ int s_carry;
  int tid = threadIdx.x;
  if (tid == 0) s_carry = 0;
  __syncthreads();
  for (int base = 0; base < NBUK; base += 1024) {
    int i = base + tid;
    int v = (i < NBUK) ? tot[i] : 0;
    buf[tid] = v;
    __syncthreads();
#pragma unroll
    for (int off = 1; off < 1024; off <<= 1) {
      int t = (tid >= off) ? buf[tid - off] : 0;
      __syncthreads();
      buf[tid] += t;
      __syncthreads();
    }
    int excl = buf[tid] - v;
    int carry = s_carry;
    if (i < NBUK) boff[i] = carry + excl;
    __syncthreads();
    if (tid == 1023) s_carry = carry + buf[1023];
    __syncthreads();
  }
  if (tid == 0) boff[NBUK] = s_carry;   // == NE
}

// pass 3: one block per chunk; LDS cursors; write packed (dstLow5,src) u32
__global__ __launch_bounds__(1024)
void k_scat(const int* __restrict__ ei, const int* __restrict__ H,
            const int* __restrict__ boff, unsigned* __restrict__ se) {
  __shared__ int cur[NBUK];
  int chunk = blockIdx.x;
  const int* Hc = H + chunk * NBUK;
  for (int i = threadIdx.x; i < NBUK; i += 1024) cur[i] = boff[i] + Hc[i];
  __syncthreads();
  int start = chunk * CH;
  for (int e = start + threadIdx.x; e < start + CH; e += 1024) {
    int src = ei[e], dst = ei[NE + e];
    int pos = atomicAdd(&cur[dst >> BUCK_SH], 1);
    se[pos] = ((unsigned)(dst & 31) << 20) | (unsigned)src;   // src < 2^17
  }
}

// one block per bucket: local counting sort -> rowptr, dis, csr_src
__global__ __launch_bounds__(256)
void k_blocal(const unsigned* __restrict__ se, const int* __restrict__ boff,
              int* __restrict__ rowptr, float* __restrict__ dis, int* __restrict__ csr_src) {
  int b = blockIdx.x;
  int base = boff[b], end = boff[b + 1];
  __shared__ int cnt[32], off[32];
  int tid = threadIdx.x;
  if (tid < 32) cnt[tid] = 0;
  __syncthreads();
  for (int k = base + tid; k < end; k += 256)
    atomicAdd(&cnt[se[k] >> 20], 1);
  __syncthreads();
  if (tid == 0) {
    int acc = 0;
#pragma unroll
    for (int i = 0; i < 32; ++i) { off[i] = acc; acc += cnt[i]; }
  }
  __syncthreads();
  if (tid < 32) {
    int node = (b << BUCK_SH) + tid;
    rowptr[node] = base + off[tid];
    dis[node] = rsqrtf(1.0f + (float)cnt[tid]);
    cnt[tid] = 0;                       // reuse as cursor
  }
  if (b == 0 && tid == 64) rowptr[NN] = NE;
  __syncthreads();
  for (int k = base + tid; k < end; k += 256) {
    unsigned e = se[k];
    int dl = e >> 20;
    int pos = base + off[dl] + atomicAdd(&cnt[dl], 1);
    csr_src[pos] = (int)(e & 0xFFFFFu);
  }
}

// GEMM 64->64, fp16 out, W-column in registers, no LDS.
__global__ __launch_bounds__(256)
void k_gemm64_h(const float* __restrict__ in, const float* __restrict__ W,
                const float* __restrict__ dis, __half* __restrict__ g) {
  int c = threadIdx.x & 63;
  int wid = threadIdx.x >> 6;          // 4 waves/block
  float Wc[64];
#pragma unroll
  for (int k = 0; k < 64; ++k) Wc[k] = W[k * 64 + c];
  int nw = gridDim.x * 4;
  for (int row = blockIdx.x * 4 + wid; row < NN; row += nw) {
    const float* rp = in + (size_t)row * 64;
    float acc = 0.f;
#pragma unroll
    for (int kc = 0; kc < 64; kc += 4) {
      float4 v = *(const float4*)(rp + kc);
      acc = fmaf(v.x, Wc[kc + 0], acc);
      acc = fmaf(v.y, Wc[kc + 1], acc);
      acc = fmaf(v.z, Wc[kc + 2], acc);
      acc = fmaf(v.w, Wc[kc + 3], acc);
    }
    g[row * 64 + c] = __float2half(acc * dis[row]);
  }
}

// GEMM 64->32, fp16 out. lane&31 = column, lane>>5 = K-half; shfl_down(32) combine.
__global__ __launch_bounds__(256)
void k_gemm32_h(const float* __restrict__ in, const float* __restrict__ W,
                const float* __restrict__ dis, __half* __restrict__ g) {
  int lane = threadIdx.x & 63;
  int c = lane & 31;
  int ksub = lane >> 5;                // 0 or 1
  int wid = threadIdx.x >> 6;
  float Wc[32];
#pragma unroll
  for (int k = 0; k < 32; ++k) Wc[k] = W[(ksub * 32 + k) * 32 + c];
  int nw = gridDim.x * 4;
  for (int row = blockIdx.x * 4 + wid; row < NN; row += nw) {
    const float* rp = in + (size_t)row * 64 + ksub * 32;
    float acc = 0.f;
#pragma unroll
    for (int kc = 0; kc < 32; kc += 4) {
      float4 v = *(const float4*)(rp + kc);
      acc = fmaf(v.x, Wc[kc + 0], acc);
      acc = fmaf(v.y, Wc[kc + 1], acc);
      acc = fmaf(v.z, Wc[kc + 2], acc);
      acc = fmaf(v.w, Wc[kc + 3], acc);
    }
    acc += __shfl_down(acc, 32);       // combine K-halves
    if (ksub == 0) g[row * 32 + c] = __float2half(acc * dis[row]);
  }
}

// fp32 GEMM for the tiny last layer (32 -> 1)
template<int K, int C>
__global__ void k_gemm_scale(const float* __restrict__ in, const float* __restrict__ W,
                             const float* __restrict__ dis, float* __restrict__ g) {
  __shared__ float Ws[K * C];
  for (int t = threadIdx.x; t < K * C; t += blockDim.x) Ws[t] = W[t];
  __syncthreads();
  constexpr int R = 256 / (C > 256 ? 256 : C);
  int t = threadIdx.x;
  int rl = t / C, c = t % C;
  int row = blockIdx.x * R + rl;
  if (row >= NN) return;
  const float* inr = in + row * K;
  float acc = 0.f;
#pragma unroll
  for (int k = 0; k < K; ++k) acc += inr[k] * Ws[k * C + c];
  g[row * C + c] = acc * dis[row];
}

__device__ __forceinline__ void unpack_add4(float2 r, float4& acc) {
  __half2 h01 = *(__half2*)&r.x;
  __half2 h23 = *(__half2*)&r.y;
  float2 f01 = __half22float2(h01);
  float2 f23 = __half22float2(h23);
  acc.x += f01.x; acc.y += f01.y; acc.z += f23.x; acc.w += f23.y;
}

// C=64 agg: one wave per node; 16 lanes per edge-row (float2 = 4 halves each);
// 4 edges per wave-instruction; 2-deep unroll; shfl_xor group reduce.
template<bool TANH>
__global__ __launch_bounds__(256)
void k_agg64v(const int* __restrict__ rowptr, const int* __restrict__ csr_src,
              const __half* __restrict__ g, const float* __restrict__ dis,
              const float* __restrict__ b, float* __restrict__ out) {
  int node = blockIdx.x * 4 + (threadIdx.x >> 6);
  if (node >= NN) return;
  int lane = threadIdx.x & 63;
  int grp = lane >> 4;                 // 0..3: edge slot
  int cl = lane & 15;                  // channel quad: channels cl*4..cl*4+3
  const char* base = (const char*)g;
  float4 acc = {0.f, 0.f, 0.f, 0.f};
  int beg = rowptr[node], end = rowptr[node + 1];
  int k = beg + grp;
  for (; k + 4 < end; k += 8) {
    int s0 = csr_src[k], s1 = csr_src[k + 4];
    float2 r0 = *(const float2*)(base + (size_t)s0 * 128 + cl * 8);
    float2 r1 = *(const float2*)(base + (size_t)s1 * 128 + cl * 8);
    unpack_add4(r0, acc);
    unpack_add4(r1, acc);
  }
  for (; k < end; k += 4) {
    int s = csr_src[k];
    float2 r = *(const float2*)(base + (size_t)s * 128 + cl * 8);
    unpack_add4(r, acc);
  }
  if (grp == 0) {                      // self loop
    float2 r = *(const float2*)(base + (size_t)node * 128 + cl * 8);
    unpack_add4(r, acc);
  }
  acc.x += __shfl_xor(acc.x, 16); acc.y += __shfl_xor(acc.y, 16);
  acc.z += __shfl_xor(acc.z, 16); acc.w += __shfl_xor(acc.w, 16);
  acc.x += __shfl_xor(acc.x, 32); acc.y += __shfl_xor(acc.y, 32);
  acc.z += __shfl_xor(acc.z, 32); acc.w += __shfl_xor(acc.w, 32);
  if (grp == 0) {
    float d = dis[node];
    float4 bb = *(const float4*)(b + cl * 4);
    float4 v;
    v.x = acc.x * d + bb.x; v.y = acc.y * d + bb.y;
    v.z = acc.z * d + bb.z; v.w = acc.w * d + bb.w;
    if (TANH) { v.x = tanhf(v.x); v.y = tanhf(v.y); v.z = tanhf(v.z); v.w = tanhf(v.w); }
    *(float4*)(out + (size_t)node * 64 + cl * 4) = v;
  }
}

// C=32 agg: one wave per node; 16 lanes per edge-row (half2 = 2 halves each);
// 4 edges per wave-instruction; 2-deep unroll.
template<bool TANH>
__global__ __launch_bounds__(256)
void k_agg32v(const int* __restrict__ rowptr, const int* __restrict__ csr_src,
              const __half* __restrict__ g, const float* __restrict__ dis,
              const float* __restrict__ b, float* __restrict__ out) {
  int node = blockIdx.x * 4 + (threadIdx.x >> 6);
  if (node >= NN) return;
  int lane = threadIdx.x & 63;
  int grp = lane >> 4;                 // 0..3: edge slot
  int cl = lane & 15;                  // channel pair: channels cl*2, cl*2+1
  const char* base = (const char*)g;
  float ax = 0.f, ay = 0.f;
  int beg = rowptr[node], end = rowptr[node + 1];
  int k = beg + grp;
  for (; k + 4 < end; k += 8) {
    int s0 = csr_src[k], s1 = csr_src[k + 4];
    unsigned u0 = *(const unsigned*)(base + (size_t)s0 * 64 + cl * 4);
    unsigned u1 = *(const unsigned*)(base + (size_t)s1 * 64 + cl * 4);
    float2 f0 = __half22float2(*(__half2*)&u0);
    float2 f1 = __half22float2(*(__half2*)&u1);
    ax += f0.x + f1.x; ay += f0.y + f1.y;
  }
  for (; k < end; k += 4) {
    int s = csr_src[k];
    unsigned u = *(const unsigned*)(base + (size_t)s * 64 + cl * 4);
    float2 f = __half22float2(*(__half2*)&u);
    ax += f.x; ay += f.y;
  }
  if (grp == 0) {                      // self loop
    unsigned u = *(const unsigned*)(base + (size_t)node * 64 + cl * 4);
    float2 f = __half22float2(*(__half2*)&u);
    ax += f.x; ay += f.y;
  }
  ax += __shfl_xor(ax, 16); ay += __shfl_xor(ay, 16);
  ax += __shfl_xor(ax, 32); ay += __shfl_xor(ay, 32);
  if (grp == 0) {
    float d = dis[node];
    float2 bb = *(const float2*)(b + cl * 2);
    float vx = ax * d + bb.x, vy = ay * d + bb.y;
    if (TANH) { vx = tanhf(vx); vy = tanhf(vy); }
    float2 v = {vx, vy};
    *(float2*)(out + (size_t)node * 32 + cl * 2) = v;
  }
}

// C=1: thread per node, fp32 (tiny).
__global__ void k_agg1(const int* __restrict__ rowptr, const int* __restrict__ csr_src,
                       const float* __restrict__ g, const float* __restrict__ dis,
                       const float* __restrict__ b, float* __restrict__ out) {
  int node = blockIdx.x * blockDim.x + threadIdx.x;
  if (node >= NN) return;
  float a0 = g[node], a1 = 0.f, a2 = 0.f, a3 = 0.f;
  int beg = rowptr[node], end = rowptr[node + 1];
  int k = beg;
  for (; k + 4 <= end; k += 4) {
    float m0 = g[csr_src[k]], m1 = g[csr_src[k + 1]];
    float m2 = g[csr_src[k + 2]], m3 = g[csr_src[k + 3]];
    a0 += m0; a1 += m1; a2 += m2; a3 += m3;
  }
  for (; k < end; ++k) a0 += g[csr_src[k]];
  out[node] = ((a0 + a1) + (a2 + a3)) * dis[node] + b[0];
}

extern "C" void kernel_launch(void* const* d_in, const int* in_sizes, int n_in,
                              void* d_out, int out_size, void* d_ws, size_t ws_size,
                              hipStream_t stream) {
  const float* x  = (const float*)d_in[0];
  const int*   ei = (const int*)d_in[1];
  const float* W1 = (const float*)d_in[2];
  const float* b1 = (const float*)d_in[3];
  const float* W2 = (const float*)d_in[4];
  const float* b2 = (const float*)d_in[5];
  const float* W3 = (const float*)d_in[6];
  const float* b3 = (const float*)d_in[7];
  float* out = (float*)d_out;

  char* ws = (char*)d_ws;
  int*      H       = (int*)ws;      ws += (size_t)NCH * NBUK * 4;          // 800 KB
  int*      tot     = (int*)ws;      ws += ((NBUK + 255)/256)*256 * 4;
  int*      boff    = (int*)ws;      ws += ((NBUK + 1 + 255)/256)*256 * 4;
  unsigned* se      = (unsigned*)ws; ws += (size_t)NE * 4;                  // 6.4 MB
  int*      rowptr  = (int*)ws;      ws += ((NN + 1 + 255)/256)*256 * 4;
  int*      csr_src = (int*)ws;      ws += (size_t)NE * 4;                  // 6.4 MB
  float*    dis     = (float*)ws;    ws += ((NN + 255)/256)*256 * 4;
  __half*   Ah      = (__half*)ws;   ws += (size_t)NN * 64 * 2;             // 12.8 MB
  float*    Af      = (float*)ws;    ws += (size_t)NN * 4;
  float*    B       = (float*)ws;    // fp32 h buffer (N*64), 25.6 MB

  // ---- CSR build (deterministic two-pass counting sort) + dis
  k_zero  <<<(NCH * NBUK + 255) / 256, 256, 0, stream>>>(H, NCH * NBUK);
  k_chist <<<NCH * SUB, 256, 0, stream>>>(ei, H);
  k_csum  <<<(NBUK + 255) / 256, 256, 0, stream>>>(H, tot);
  k_bscan <<<1, 1024, 0, stream>>>(tot, boff);
  k_scat  <<<NCH, 1024, 0, stream>>>(ei, H, boff, se);
  k_blocal<<<NBUK, 256, 0, stream>>>(se, boff, rowptr, dis, csr_src);

  // ---- layer 1: 64 -> 64, tanh
  k_gemm64_h<<<1024, 256, 0, stream>>>(x, W1, dis, Ah);
  k_agg64v<true><<<(NN + 3) / 4, 256, 0, stream>>>(rowptr, csr_src, Ah, dis, b1, B);

  // ---- layer 2: 64 -> 32, tanh
  k_gemm32_h<<<1024, 256, 0, stream>>>(B, W2, dis, Ah);
  k_agg32v<true><<<(NN + 3) / 4, 256, 0, stream>>>(rowptr, csr_src, Ah, dis, b2, B);

  // ---- layer 3: 32 -> 1 (no activation) -> d_out
  k_gemm_scale<32, 1><<<(NN + 255) / 256, 256, 0, stream>>>(B, W3, dis, Af);
  k_agg1<<<(NN + 255) / 256, 256, 0, stream>>>(rowptr, csr_src, Af, dis, b3, out);
}

// Round 10
// 307.220 us; speedup vs baseline: 1.2889x; 1.1342x over previous
//
#include <hip/hip_runtime.h>
#include <hip/hip_fp16.h>
#include <math.h>

static constexpr int NN = 100000;   // nodes
static constexpr int NE = 1600000;  // edges
static constexpr int BUCK_SH = 5;   // 32 nodes per bucket
static constexpr int NBUK = NN >> BUCK_SH;   // 3125 (exact)
static constexpr int NCH = 256;              // chunks (one scat block each)
static constexpr int CH = NE / NCH;          // 6250 edges per chunk (exact)

__global__ void k_zero(int* __restrict__ p, int n) {
  int i = blockIdx.x * blockDim.x + threadIdx.x;
  if (i < n) p[i] = 0;
}

// pass 1: per-chunk bucket histogram H[chunk][bucket], LDS-staged
__global__ __launch_bounds__(256)
void k_chist(const int* __restrict__ ei, int* __restrict__ H) {
  __shared__ int h[NBUK];
  for (int i = threadIdx.x; i < NBUK; i += 256) h[i] = 0;
  __syncthreads();
  int chunk = blockIdx.x;
  int start = chunk * CH;
  for (int e = start + threadIdx.x; e < start + CH; e += 256)
    atomicAdd(&h[ei[NE + e] >> BUCK_SH], 1);
  __syncthreads();
  int* Hc = H + chunk * NBUK;
  for (int i = threadIdx.x; i < NBUK; i += 256) Hc[i] = h[i];
}

// pass 2: in-place exclusive prefix over chunks per bucket; totals -> tot
__global__ void k_csum(int* __restrict__ H, int* __restrict__ tot) {
  int b = blockIdx.x * blockDim.x + threadIdx.x;
  if (b >= NBUK) return;
  int acc = 0;
#pragma unroll 4
  for (int c = 0; c < NCH; ++c) {
    int v = H[c * NBUK + b];
    H[c * NBUK + b] = acc;
    acc += v;
  }
  tot[b] = acc;
}

// single-block scan of bucket totals -> boff (exclusive), boff[NBUK]=NE
__global__ __launch_bounds__(1024)
void k_bscan(const int* __restrict__ tot, int* __restrict__ boff) {
  __shared__ int buf[1024];
  __shared__ int s_carry;
  int tid = threadIdx.x;
  if (tid == 0) s_carry = 0;
  __syncthreads();
  for (int base = 0; base < NBUK; base += 1024) {
    int i = base + tid;
    int v = (i < NBUK) ? tot[i] : 0;
    buf[tid] = v;
    __syncthreads();
#pragma unroll
    for (int off = 1; off < 1024; off <<= 1) {
      int t = (tid >= off) ? buf[tid - off] : 0;
      __syncthreads();
      buf[tid] += t;
      __syncthreads();
    }
    int excl = buf[tid] - v;
    int carry = s_carry;
    if (i < NBUK) boff[i] = carry + excl;
    __syncthreads();
    if (tid == 1023) s_carry = carry + buf[1023];
    __syncthreads();
  }
  if (tid == 0) boff[NBUK] = s_carry;   // == NE
}

// pass 3: one block per chunk; LDS cursors; write packed (dstLow5,src) u32
__global__ __launch_bounds__(1024)
void k_scat(const int* __restrict__ ei, const int* __restrict__ H,
            const int* __restrict__ boff, unsigned* __restrict__ se) {
  __shared__ int cur[NBUK];
  int chunk = blockIdx.x;
  const int* Hc = H + chunk * NBUK;
  for (int i = threadIdx.x; i < NBUK; i += 1024) cur[i] = boff[i] + Hc[i];
  __syncthreads();
  int start = chunk * CH;
  for (int e = start + threadIdx.x; e < start + CH; e += 1024) {
    int src = ei[e], dst = ei[NE + e];
    int pos = atomicAdd(&cur[dst >> BUCK_SH], 1);
    se[pos] = ((unsigned)(dst & 31) << 20) | (unsigned)src;   // src < 2^17
  }
}

// one block per bucket: local counting sort -> rowptr, dis, csr_src
__global__ __launch_bounds__(256)
void k_blocal(const unsigned* __restrict__ se, const int* __restrict__ boff,
              int* __restrict__ rowptr, float* __restrict__ dis, int* __restrict__ csr_src) {
  int b = blockIdx.x;
  int base = boff[b], end = boff[b + 1];
  __shared__ int cnt[32], off[32];
  int tid = threadIdx.x;
  if (tid < 32) cnt[tid] = 0;
  __syncthreads();
  for (int k = base + tid; k < end; k += 256)
    atomicAdd(&cnt[se[k] >> 20], 1);
  __syncthreads();
  if (tid == 0) {
    int acc = 0;
#pragma unroll
    for (int i = 0; i < 32; ++i) { off[i] = acc; acc += cnt[i]; }
  }
  __syncthreads();
  if (tid < 32) {
    int node = (b << BUCK_SH) + tid;
    rowptr[node] = base + off[tid];
    dis[node] = rsqrtf(1.0f + (float)cnt[tid]);
    cnt[tid] = 0;                       // reuse as cursor
  }
  if (b == 0 && tid == 64) rowptr[NN] = NE;
  __syncthreads();
  for (int k = base + tid; k < end; k += 256) {
    unsigned e = se[k];
    int dl = e >> 20;
    int pos = base + off[dl] + atomicAdd(&cnt[dl], 1);
    csr_src[pos] = (int)(e & 0xFFFFFu);
  }
}

// GEMM 64->64, fp16 out. W-column in registers; input rows staged in LDS
// (coalesced float4), read back as wave-uniform ds_read_b128 broadcasts.
// 16-row tiles; NN = 16*6250 exactly; grid 1250 -> 5 tiles/block.
__global__ __launch_bounds__(256)
void k_gemm64_h(const float* __restrict__ in, const float* __restrict__ W,
                const float* __restrict__ dis, __half* __restrict__ g) {
  __shared__ float rows[16 * 64];      // 4 KB
  int c = threadIdx.x & 63;
  int wid = threadIdx.x >> 6;          // 4 waves/block
  float Wc[64];
#pragma unroll
  for (int k = 0; k < 64; ++k) Wc[k] = W[k * 64 + c];
  int tiles = NN / 16;                 // 6250
  for (int t = blockIdx.x; t < tiles; t += gridDim.x) {
    int row0 = t * 16;
    __syncthreads();
    ((float4*)rows)[threadIdx.x] = ((const float4*)(in + (size_t)row0 * 64))[threadIdx.x];
    __syncthreads();
#pragma unroll
    for (int r = 0; r < 4; ++r) {
      const float* rp = rows + (wid * 4 + r) * 64;
      float acc = 0.f;
#pragma unroll
      for (int kc = 0; kc < 64; kc += 4) {
        float4 v = *(const float4*)(rp + kc);   // broadcast ds_read_b128
        acc = fmaf(v.x, Wc[kc + 0], acc);
        acc = fmaf(v.y, Wc[kc + 1], acc);
        acc = fmaf(v.z, Wc[kc + 2], acc);
        acc = fmaf(v.w, Wc[kc + 3], acc);
      }
      int row = row0 + wid * 4 + r;
      g[row * 64 + c] = __float2half(acc * dis[row]);
    }
  }
}

// GEMM 64->32, fp16 out. lane&31 = column, lane>>5 = K-half; LDS row staging;
// shfl_down(32) combines K-halves. 2-way LDS aliasing across halves is free.
__global__ __launch_bounds__(256)
void k_gemm32_h(const float* __restrict__ in, const float* __restrict__ W,
                const float* __restrict__ dis, __half* __restrict__ g) {
  __shared__ float rows[16 * 64];      // 4 KB
  int lane = threadIdx.x & 63;
  int c = lane & 31;
  int ksub = lane >> 5;                // 0 or 1
  int wid = threadIdx.x >> 6;
  float Wc[32];
#pragma unroll
  for (int k = 0; k < 32; ++k) Wc[k] = W[(ksub * 32 + k) * 32 + c];
  int tiles = NN / 16;
  for (int t = blockIdx.x; t < tiles; t += gridDim.x) {
    int row0 = t * 16;
    __syncthreads();
    ((float4*)rows)[threadIdx.x] = ((const float4*)(in + (size_t)row0 * 64))[threadIdx.x];
    __syncthreads();
#pragma unroll
    for (int r = 0; r < 4; ++r) {
      const float* rp = rows + (wid * 4 + r) * 64 + ksub * 32;
      float acc = 0.f;
#pragma unroll
      for (int kc = 0; kc < 32; kc += 4) {
        float4 v = *(const float4*)(rp + kc);
        acc = fmaf(v.x, Wc[kc + 0], acc);
        acc = fmaf(v.y, Wc[kc + 1], acc);
        acc = fmaf(v.z, Wc[kc + 2], acc);
        acc = fmaf(v.w, Wc[kc + 3], acc);
      }
      acc += __shfl_down(acc, 32);     // combine K-halves
      int row = row0 + wid * 4 + r;
      if (ksub == 0) g[row * 32 + c] = __float2half(acc * dis[row]);
    }
  }
}

// fp32 GEMM for the tiny last layer (32 -> 1)
template<int K, int C>
__global__ void k_gemm_scale(const float* __restrict__ in, const float* __restrict__ W,
                             const float* __restrict__ dis, float* __restrict__ g) {
  __shared__ float Ws[K * C];
  for (int t = threadIdx.x; t < K * C; t += blockDim.x) Ws[t] = W[t];
  __syncthreads();
  constexpr int R = 256 / (C > 256 ? 256 : C);
  int t = threadIdx.x;
  int rl = t / C, c = t % C;
  int row = blockIdx.x * R + rl;
  if (row >= NN) return;
  const float* inr = in + row * K;
  float acc = 0.f;
#pragma unroll
  for (int k = 0; k < K; ++k) acc += inr[k] * Ws[k * C + c];
  g[row * C + c] = acc * dis[row];
}

__device__ __forceinline__ void unpack_add4(float2 r, float4& acc) {
  __half2 h01 = *(__half2*)&r.x;
  __half2 h23 = *(__half2*)&r.y;
  float2 f01 = __half22float2(h01);
  float2 f23 = __half22float2(h23);
  acc.x += f01.x; acc.y += f01.y; acc.z += f23.x; acc.w += f23.y;
}

// C=64 agg: one wave per node; 16 lanes per edge-row (float2 = 4 halves each);
// 4 edges per wave-instruction; 2-deep unroll; shfl_xor group reduce.
template<bool TANH>
__global__ __launch_bounds__(256)
void k_agg64v(const int* __restrict__ rowptr, const int* __restrict__ csr_src,
              const __half* __restrict__ g, const float* __restrict__ dis,
              const float* __restrict__ b, float* __restrict__ out) {
  int node = blockIdx.x * 4 + (threadIdx.x >> 6);
  if (node >= NN) return;
  int lane = threadIdx.x & 63;
  int grp = lane >> 4;                 // 0..3: edge slot
  int cl = lane & 15;                  // channel quad: channels cl*4..cl*4+3
  const char* base = (const char*)g;
  float4 acc = {0.f, 0.f, 0.f, 0.f};
  int beg = rowptr[node], end = rowptr[node + 1];
  int k = beg + grp;
  for (; k + 4 < end; k += 8) {
    int s0 = csr_src[k], s1 = csr_src[k + 4];
    float2 r0 = *(const float2*)(base + (size_t)s0 * 128 + cl * 8);
    float2 r1 = *(const float2*)(base + (size_t)s1 * 128 + cl * 8);
    unpack_add4(r0, acc);
    unpack_add4(r1, acc);
  }
  for (; k < end; k += 4) {
    int s = csr_src[k];
    float2 r = *(const float2*)(base + (size_t)s * 128 + cl * 8);
    unpack_add4(r, acc);
  }
  if (grp == 0) {                      // self loop
    float2 r = *(const float2*)(base + (size_t)node * 128 + cl * 8);
    unpack_add4(r, acc);
  }
  acc.x += __shfl_xor(acc.x, 16); acc.y += __shfl_xor(acc.y, 16);
  acc.z += __shfl_xor(acc.z, 16); acc.w += __shfl_xor(acc.w, 16);
  acc.x += __shfl_xor(acc.x, 32); acc.y += __shfl_xor(acc.y, 32);
  acc.z += __shfl_xor(acc.z, 32); acc.w += __shfl_xor(acc.w, 32);
  if (grp == 0) {
    float d = dis[node];
    float4 bb = *(const float4*)(b + cl * 4);
    float4 v;
    v.x = acc.x * d + bb.x; v.y = acc.y * d + bb.y;
    v.z = acc.z * d + bb.z; v.w = acc.w * d + bb.w;
    if (TANH) { v.x = tanhf(v.x); v.y = tanhf(v.y); v.z = tanhf(v.z); v.w = tanhf(v.w); }
    *(float4*)(out + (size_t)node * 64 + cl * 4) = v;
  }
}

// C=32 agg: one wave per node; 16 lanes per edge-row (half2 = 2 halves each).
template<bool TANH>
__global__ __launch_bounds__(256)
void k_agg32v(const int* __restrict__ rowptr, const int* __restrict__ csr_src,
              const __half* __restrict__ g, const float* __restrict__ dis,
              const float* __restrict__ b, float* __restrict__ out) {
  int node = blockIdx.x * 4 + (threadIdx.x >> 6);
  if (node >= NN) return;
  int lane = threadIdx.x & 63;
  int grp = lane >> 4;                 // 0..3: edge slot
  int cl = lane & 15;                  // channel pair: channels cl*2, cl*2+1
  const char* base = (const char*)g;
  float ax = 0.f, ay = 0.f;
  int beg = rowptr[node], end = rowptr[node + 1];
  int k = beg + grp;
  for (; k + 4 < end; k += 8) {
    int s0 = csr_src[k], s1 = csr_src[k + 4];
    unsigned u0 = *(const unsigned*)(base + (size_t)s0 * 64 + cl * 4);
    unsigned u1 = *(const unsigned*)(base + (size_t)s1 * 64 + cl * 4);
    float2 f0 = __half22float2(*(__half2*)&u0);
    float2 f1 = __half22float2(*(__half2*)&u1);
    ax += f0.x + f1.x; ay += f0.y + f1.y;
  }
  for (; k < end; k += 4) {
    int s = csr_src[k];
    unsigned u = *(const unsigned*)(base + (size_t)s * 64 + cl * 4);
    float2 f = __half22float2(*(__half2*)&u);
    ax += f.x; ay += f.y;
  }
  if (grp == 0) {                      // self loop
    unsigned u = *(const unsigned*)(base + (size_t)node * 64 + cl * 4);
    float2 f = __half22float2(*(__half2*)&u);
    ax += f.x; ay += f.y;
  }
  ax += __shfl_xor(ax, 16); ay += __shfl_xor(ay, 16);
  ax += __shfl_xor(ax, 32); ay += __shfl_xor(ay, 32);
  if (grp == 0) {
    float d = dis[node];
    float2 bb = *(const float2*)(b + cl * 2);
    float vx = ax * d + bb.x, vy = ay * d + bb.y;
    if (TANH) { vx = tanhf(vx); vy = tanhf(vy); }
    float2 v = {vx, vy};
    *(float2*)(out + (size_t)node * 32 + cl * 2) = v;
  }
}

// C=1: thread per node, fp32 (tiny).
__global__ void k_agg1(const int* __restrict__ rowptr, const int* __restrict__ csr_src,
                       const float* __restrict__ g, const float* __restrict__ dis,
                       const float* __restrict__ b, float* __restrict__ out) {
  int node = blockIdx.x * blockDim.x + threadIdx.x;
  if (node >= NN) return;
  float a0 = g[node], a1 = 0.f, a2 = 0.f, a3 = 0.f;
  int beg = rowptr[node], end = rowptr[node + 1];
  int k = beg;
  for (; k + 4 <= end; k += 4) {
    float m0 = g[csr_src[k]], m1 = g[csr_src[k + 1]];
    float m2 = g[csr_src[k + 2]], m3 = g[csr_src[k + 3]];
    a0 += m0; a1 += m1; a2 += m2; a3 += m3;
  }
  for (; k < end; ++k) a0 += g[csr_src[k]];
  out[node] = ((a0 + a1) + (a2 + a3)) * dis[node] + b[0];
}

extern "C" void kernel_launch(void* const* d_in, const int* in_sizes, int n_in,
                              void* d_out, int out_size, void* d_ws, size_t ws_size,
                              hipStream_t stream) {
  const float* x  = (const float*)d_in[0];
  const int*   ei = (const int*)d_in[1];
  const float* W1 = (const float*)d_in[2];
  const float* b1 = (const float*)d_in[3];
  const float* W2 = (const float*)d_in[4];
  const float* b2 = (const float*)d_in[5];
  const float* W3 = (const float*)d_in[6];
  const float* b3 = (const float*)d_in[7];
  float* out = (float*)d_out;

  char* ws = (char*)d_ws;
  int*      H       = (int*)ws;      ws += (size_t)NCH * NBUK * 4;          // 3.2 MB
  int*      tot     = (int*)ws;      ws += ((NBUK + 255)/256)*256 * 4;
  int*      boff    = (int*)ws;      ws += ((NBUK + 1 + 255)/256)*256 * 4;
  unsigned* se      = (unsigned*)ws; ws += (size_t)NE * 4;                  // 6.4 MB
  int*      rowptr  = (int*)ws;      ws += ((NN + 1 + 255)/256)*256 * 4;
  int*      csr_src = (int*)ws;      ws += (size_t)NE * 4;                  // 6.4 MB
  float*    dis     = (float*)ws;    ws += ((NN + 255)/256)*256 * 4;
  __half*   Ah      = (__half*)ws;   ws += (size_t)NN * 64 * 2;             // 12.8 MB
  float*    Af      = (float*)ws;    ws += (size_t)NN * 4;
  float*    B       = (float*)ws;    // fp32 h buffer (N*64), 25.6 MB

  // ---- CSR build (deterministic two-pass counting sort) + dis
  k_zero  <<<(NCH * NBUK + 255) / 256, 256, 0, stream>>>(H, NCH * NBUK);
  k_chist <<<NCH, 256, 0, stream>>>(ei, H);
  k_csum  <<<(NBUK + 255) / 256, 256, 0, stream>>>(H, tot);
  k_bscan <<<1, 1024, 0, stream>>>(tot, boff);
  k_scat  <<<NCH, 1024, 0, stream>>>(ei, H, boff, se);
  k_blocal<<<NBUK, 256, 0, stream>>>(se, boff, rowptr, dis, csr_src);

  // ---- layer 1: 64 -> 64, tanh
  k_gemm64_h<<<1250, 256, 0, stream>>>(x, W1, dis, Ah);
  k_agg64v<true><<<(NN + 3) / 4, 256, 0, stream>>>(rowptr, csr_src, Ah, dis, b1, B);

  // ---- layer 2: 64 -> 32, tanh
  k_gemm32_h<<<1250, 256, 0, stream>>>(B, W2, dis, Ah);
  k_agg32v<true><<<(NN + 3) / 4, 256, 0, stream>>>(rowptr, csr_src, Ah, dis, b2, B);

  // ---- layer 3: 32 -> 1 (no activation) -> d_out
  k_gemm_scale<32, 1><<<(NN + 255) / 256, 256, 0, stream>>>(B, W3, dis, Af);
  k_agg1<<<(NN + 255) / 256, 256, 0, stream>>>(rowptr, csr_src, Af, dis, b3, out);
}

// Round 11
// 285.279 us; speedup vs baseline: 1.3880x; 1.0769x over previous
//
#include <hip/hip_runtime.h>
#include <hip/hip_fp16.h>
#include <math.h>

static constexpr int NN = 100000;   // nodes
static constexpr int NE = 1600000;  // edges
static constexpr int BUCK_SH = 5;   // 32 nodes per bucket
static constexpr int NBUK = NN >> BUCK_SH;   // 3125 (exact)
static constexpr int NCH = 256;              // chunks (one scat block each)
static constexpr int CH = NE / NCH;          // 6250 edges per chunk (exact)

__global__ void k_zero(int* __restrict__ p, int n) {
  int i = blockIdx.x * blockDim.x + threadIdx.x;
  if (i < n) p[i] = 0;
}

// pass 1: per-chunk bucket histogram H[chunk][bucket], LDS-staged
__global__ __launch_bounds__(256)
void k_chist(const int* __restrict__ ei, int* __restrict__ H) {
  __shared__ int h[NBUK];
  for (int i = threadIdx.x; i < NBUK; i += 256) h[i] = 0;
  __syncthreads();
  int chunk = blockIdx.x;
  int start = chunk * CH;
  for (int e = start + threadIdx.x; e < start + CH; e += 256)
    atomicAdd(&h[ei[NE + e] >> BUCK_SH], 1);
  __syncthreads();
  int* Hc = H + chunk * NBUK;
  for (int i = threadIdx.x; i < NBUK; i += 256) Hc[i] = h[i];
}

// pass 2: in-place exclusive prefix over chunks per bucket; totals -> tot
__global__ void k_csum(int* __restrict__ H, int* __restrict__ tot) {
  int b = blockIdx.x * blockDim.x + threadIdx.x;
  if (b >= NBUK) return;
  int acc = 0;
#pragma unroll 4
  for (int c = 0; c < NCH; ++c) {
    int v = H[c * NBUK + b];
    H[c * NBUK + b] = acc;
    acc += v;
  }
  tot[b] = acc;
}

// single-block scan of bucket totals -> boff (exclusive), boff[NBUK]=NE
__global__ __launch_bounds__(1024)
void k_bscan(const int* __restrict__ tot, int* __restrict__ boff) {
  __shared__ int buf[1024];
  __shared__ int s_carry;
  int tid = threadIdx.x;
  if (tid == 0) s_carry = 0;
  __syncthreads();
  for (int base = 0; base < NBUK; base += 1024) {
    int i = base + tid;
    int v = (i < NBUK) ? tot[i] : 0;
    buf[tid] = v;
    __syncthreads();
#pragma unroll
    for (int off = 1; off < 1024; off <<= 1) {
      int t = (tid >= off) ? buf[tid - off] : 0;
      __syncthreads();
      buf[tid] += t;
      __syncthreads();
    }
    int excl = buf[tid] - v;
    int carry = s_carry;
    if (i < NBUK) boff[i] = carry + excl;
    __syncthreads();
    if (tid == 1023) s_carry = carry + buf[1023];
    __syncthreads();
  }
  if (tid == 0) boff[NBUK] = s_carry;   // == NE
}

// pass 3: one block per chunk; LDS cursors; write packed (dstLow5,src) u32
__global__ __launch_bounds__(1024)
void k_scat(const int* __restrict__ ei, const int* __restrict__ H,
            const int* __restrict__ boff, unsigned* __restrict__ se) {
  __shared__ int cur[NBUK];
  int chunk = blockIdx.x;
  const int* Hc = H + chunk * NBUK;
  for (int i = threadIdx.x; i < NBUK; i += 1024) cur[i] = boff[i] + Hc[i];
  __syncthreads();
  int start = chunk * CH;
  for (int e = start + threadIdx.x; e < start + CH; e += 1024) {
    int src = ei[e], dst = ei[NE + e];
    int pos = atomicAdd(&cur[dst >> BUCK_SH], 1);
    se[pos] = ((unsigned)(dst & 31) << 20) | (unsigned)src;   // src < 2^17
  }
}

// one block per bucket: local counting sort -> rowptr, dis, csr_src
__global__ __launch_bounds__(256)
void k_blocal(const unsigned* __restrict__ se, const int* __restrict__ boff,
              int* __restrict__ rowptr, float* __restrict__ dis, int* __restrict__ csr_src) {
  int b = blockIdx.x;
  int base = boff[b], end = boff[b + 1];
  __shared__ int cnt[32], off[32];
  int tid = threadIdx.x;
  if (tid < 32) cnt[tid] = 0;
  __syncthreads();
  for (int k = base + tid; k < end; k += 256)
    atomicAdd(&cnt[se[k] >> 20], 1);
  __syncthreads();
  if (tid == 0) {
    int acc = 0;
#pragma unroll
    for (int i = 0; i < 32; ++i) { off[i] = acc; acc += cnt[i]; }
  }
  __syncthreads();
  if (tid < 32) {
    int node = (b << BUCK_SH) + tid;
    rowptr[node] = base + off[tid];
    dis[node] = rsqrtf(1.0f + (float)cnt[tid]);
    cnt[tid] = 0;                       // reuse as cursor
  }
  if (b == 0 && tid == 64) rowptr[NN] = NE;
  __syncthreads();
  for (int k = base + tid; k < end; k += 256) {
    unsigned e = se[k];
    int dl = e >> 20;
    int pos = base + off[dl] + atomicAdd(&cnt[dl], 1);
    csr_src[pos] = (int)(e & 0xFFFFFu);
  }
}

// GEMM 64->64, fp16 out. W-column in registers; rows staged in LDS.
__global__ __launch_bounds__(256)
void k_gemm64_h(const float* __restrict__ in, const float* __restrict__ W,
                const float* __restrict__ dis, __half* __restrict__ g) {
  __shared__ float rows[16 * 64];      // 4 KB
  int c = threadIdx.x & 63;
  int wid = threadIdx.x >> 6;          // 4 waves/block
  float Wc[64];
#pragma unroll
  for (int k = 0; k < 64; ++k) Wc[k] = W[k * 64 + c];
  int tiles = NN / 16;                 // 6250
  for (int t = blockIdx.x; t < tiles; t += gridDim.x) {
    int row0 = t * 16;
    __syncthreads();
    ((float4*)rows)[threadIdx.x] = ((const float4*)(in + (size_t)row0 * 64))[threadIdx.x];
    __syncthreads();
#pragma unroll
    for (int r = 0; r < 4; ++r) {
      const float* rp = rows + (wid * 4 + r) * 64;
      float acc = 0.f;
#pragma unroll
      for (int kc = 0; kc < 64; kc += 4) {
        float4 v = *(const float4*)(rp + kc);   // broadcast ds_read_b128
        acc = fmaf(v.x, Wc[kc + 0], acc);
        acc = fmaf(v.y, Wc[kc + 1], acc);
        acc = fmaf(v.z, Wc[kc + 2], acc);
        acc = fmaf(v.w, Wc[kc + 3], acc);
      }
      int row = row0 + wid * 4 + r;
      g[row * 64 + c] = __float2half(acc * dis[row]);
    }
  }
}

// GEMM 64->32, fp16 out. lane&31 = column, lane>>5 = K-half; LDS row staging.
__global__ __launch_bounds__(256)
void k_gemm32_h(const float* __restrict__ in, const float* __restrict__ W,
                const float* __restrict__ dis, __half* __restrict__ g) {
  __shared__ float rows[16 * 64];      // 4 KB
  int lane = threadIdx.x & 63;
  int c = lane & 31;
  int ksub = lane >> 5;                // 0 or 1
  int wid = threadIdx.x >> 6;
  float Wc[32];
#pragma unroll
  for (int k = 0; k < 32; ++k) Wc[k] = W[(ksub * 32 + k) * 32 + c];
  int tiles = NN / 16;
  for (int t = blockIdx.x; t < tiles; t += gridDim.x) {
    int row0 = t * 16;
    __syncthreads();
    ((float4*)rows)[threadIdx.x] = ((const float4*)(in + (size_t)row0 * 64))[threadIdx.x];
    __syncthreads();
#pragma unroll
    for (int r = 0; r < 4; ++r) {
      const float* rp = rows + (wid * 4 + r) * 64 + ksub * 32;
      float acc = 0.f;
#pragma unroll
      for (int kc = 0; kc < 32; kc += 4) {
        float4 v = *(const float4*)(rp + kc);
        acc = fmaf(v.x, Wc[kc + 0], acc);
        acc = fmaf(v.y, Wc[kc + 1], acc);
        acc = fmaf(v.z, Wc[kc + 2], acc);
        acc = fmaf(v.w, Wc[kc + 3], acc);
      }
      acc += __shfl_down(acc, 32);     // combine K-halves
      int row = row0 + wid * 4 + r;
      if (ksub == 0) g[row * 32 + c] = __float2half(acc * dis[row]);
    }
  }
}

// fp32 GEMM for the tiny last layer (32 -> 1)
template<int K, int C>
__global__ void k_gemm_scale(const float* __restrict__ in, const float* __restrict__ W,
                             const float* __restrict__ dis, float* __restrict__ g) {
  __shared__ float Ws[K * C];
  for (int t = threadIdx.x; t < K * C; t += blockDim.x) Ws[t] = W[t];
  __syncthreads();
  constexpr int R = 256 / (C > 256 ? 256 : C);
  int t = threadIdx.x;
  int rl = t / C, c = t % C;
  int row = blockIdx.x * R + rl;
  if (row >= NN) return;
  const float* inr = in + row * K;
  float acc = 0.f;
#pragma unroll
  for (int k = 0; k < K; ++k) acc += inr[k] * Ws[k * C + c];
  g[row * C + c] = acc * dis[row];
}

__device__ __forceinline__ void unpack_add4(float2 r, float4& acc) {
  __half2 h01 = *(__half2*)&r.x;
  __half2 h23 = *(__half2*)&r.y;
  float2 f01 = __half22float2(h01);
  float2 f23 = __half22float2(h23);
  acc.x += f01.x; acc.y += f01.y; acc.z += f23.x; acc.w += f23.y;
}

// fast tanh: 1 - 2/(e^{2x}+1); saturates correctly (e->inf => 1, e->0 => -1)
__device__ __forceinline__ float fast_tanh(float x) {
  float e = __expf(2.0f * x);
  return 1.0f - 2.0f / (e + 1.0f);
}

// C=64 agg: 4 nodes per wave. Group g (16 lanes) owns node base+g and walks
// its own edge list; lane cl covers channels cl*4..cl*4+3 (float2 fp16).
// No cross-lane reduction; epilogue for all 4 nodes computed in parallel.
template<bool TANH>
__global__ __launch_bounds__(256)
void k_agg64v(const int* __restrict__ rowptr, const int* __restrict__ csr_src,
              const __half* __restrict__ g, const float* __restrict__ dis,
              const float* __restrict__ b, float* __restrict__ out) {
  int lane = threadIdx.x & 63;
  int grp = lane >> 4;                 // node slot within wave
  int cl = lane & 15;                  // channel quad
  int node = blockIdx.x * 16 + (threadIdx.x >> 6) * 4 + grp;
  if (node >= NN) return;
  const char* base = (const char*)g;
  float4 a0 = {0.f, 0.f, 0.f, 0.f}, a1 = {0.f, 0.f, 0.f, 0.f};
  {                                    // self loop
    float2 r = *(const float2*)(base + (size_t)node * 128 + cl * 8);
    unpack_add4(r, a0);
  }
  int k = rowptr[node], end = rowptr[node + 1];
  for (; k + 2 <= end; k += 2) {
    int s0 = csr_src[k], s1 = csr_src[k + 1];
    float2 r0 = *(const float2*)(base + (size_t)s0 * 128 + cl * 8);
    float2 r1 = *(const float2*)(base + (size_t)s1 * 128 + cl * 8);
    unpack_add4(r0, a0);
    unpack_add4(r1, a1);
  }
  if (k < end) {
    float2 r = *(const float2*)(base + (size_t)csr_src[k] * 128 + cl * 8);
    unpack_add4(r, a0);
  }
  float d = dis[node];
  float4 bb = *(const float4*)(b + cl * 4);
  float4 v;
  v.x = (a0.x + a1.x) * d + bb.x; v.y = (a0.y + a1.y) * d + bb.y;
  v.z = (a0.z + a1.z) * d + bb.z; v.w = (a0.w + a1.w) * d + bb.w;
  if (TANH) {
    v.x = fast_tanh(v.x); v.y = fast_tanh(v.y);
    v.z = fast_tanh(v.z); v.w = fast_tanh(v.w);
  }
  *(float4*)(out + (size_t)node * 64 + cl * 4) = v;
}

// C=32 agg: 4 nodes per wave; lane cl covers channels cl*2, cl*2+1 (half2).
template<bool TANH>
__global__ __launch_bounds__(256)
void k_agg32v(const int* __restrict__ rowptr, const int* __restrict__ csr_src,
              const __half* __restrict__ g, const float* __restrict__ dis,
              const float* __restrict__ b, float* __restrict__ out) {
  int lane = threadIdx.x & 63;
  int grp = lane >> 4;
  int cl = lane & 15;
  int node = blockIdx.x * 16 + (threadIdx.x >> 6) * 4 + grp;
  if (node >= NN) return;
  const char* base = (const char*)g;
  float ax0 = 0.f, ay0 = 0.f, ax1 = 0.f, ay1 = 0.f;
  {                                    // self loop
    unsigned u = *(const unsigned*)(base + (size_t)node * 64 + cl * 4);
    float2 f = __half22float2(*(__half2*)&u);
    ax0 += f.x; ay0 += f.y;
  }
  int k = rowptr[node], end = rowptr[node + 1];
  for (; k + 2 <= end; k += 2) {
    int s0 = csr_src[k], s1 = csr_src[k + 1];
    unsigned u0 = *(const unsigned*)(base + (size_t)s0 * 64 + cl * 4);
    unsigned u1 = *(const unsigned*)(base + (size_t)s1 * 64 + cl * 4);
    float2 f0 = __half22float2(*(__half2*)&u0);
    float2 f1 = __half22float2(*(__half2*)&u1);
    ax0 += f0.x; ay0 += f0.y;
    ax1 += f1.x; ay1 += f1.y;
  }
  if (k < end) {
    unsigned u = *(const unsigned*)(base + (size_t)csr_src[k] * 64 + cl * 4);
    float2 f = __half22float2(*(__half2*)&u);
    ax0 += f.x; ay0 += f.y;
  }
  float d = dis[node];
  float2 bb = *(const float2*)(b + cl * 2);
  float vx = (ax0 + ax1) * d + bb.x, vy = (ay0 + ay1) * d + bb.y;
  if (TANH) { vx = fast_tanh(vx); vy = fast_tanh(vy); }
  float2 v = {vx, vy};
  *(float2*)(out + (size_t)node * 32 + cl * 2) = v;
}

// C=1: thread per node, fp32 (tiny).
__global__ void k_agg1(const int* __restrict__ rowptr, const int* __restrict__ csr_src,
                       const float* __restrict__ g, const float* __restrict__ dis,
                       const float* __restrict__ b, float* __restrict__ out) {
  int node = blockIdx.x * blockDim.x + threadIdx.x;
  if (node >= NN) return;
  float a0 = g[node], a1 = 0.f, a2 = 0.f, a3 = 0.f;
  int beg = rowptr[node], end = rowptr[node + 1];
  int k = beg;
  for (; k + 4 <= end; k += 4) {
    float m0 = g[csr_src[k]], m1 = g[csr_src[k + 1]];
    float m2 = g[csr_src[k + 2]], m3 = g[csr_src[k + 3]];
    a0 += m0; a1 += m1; a2 += m2; a3 += m3;
  }
  for (; k < end; ++k) a0 += g[csr_src[k]];
  out[node] = ((a0 + a1) + (a2 + a3)) * dis[node] + b[0];
}

extern "C" void kernel_launch(void* const* d_in, const int* in_sizes, int n_in,
                              void* d_out, int out_size, void* d_ws, size_t ws_size,
                              hipStream_t stream) {
  const float* x  = (const float*)d_in[0];
  const int*   ei = (const int*)d_in[1];
  const float* W1 = (const float*)d_in[2];
  const float* b1 = (const float*)d_in[3];
  const float* W2 = (const float*)d_in[4];
  const float* b2 = (const float*)d_in[5];
  const float* W3 = (const float*)d_in[6];
  const float* b3 = (const float*)d_in[7];
  float* out = (float*)d_out;

  char* ws = (char*)d_ws;
  int*      H       = (int*)ws;      ws += (size_t)NCH * NBUK * 4;          // 3.2 MB
  int*      tot     = (int*)ws;      ws += ((NBUK + 255)/256)*256 * 4;
  int*      boff    = (int*)ws;      ws += ((NBUK + 1 + 255)/256)*256 * 4;
  unsigned* se      = (unsigned*)ws; ws += (size_t)NE * 4;                  // 6.4 MB
  int*      rowptr  = (int*)ws;      ws += ((NN + 1 + 255)/256)*256 * 4;
  int*      csr_src = (int*)ws;      ws += (size_t)NE * 4;                  // 6.4 MB
  float*    dis     = (float*)ws;    ws += ((NN + 255)/256)*256 * 4;
  __half*   Ah      = (__half*)ws;   ws += (size_t)NN * 64 * 2;             // 12.8 MB
  float*    Af      = (float*)ws;    ws += (size_t)NN * 4;
  float*    B       = (float*)ws;    // fp32 h buffer (N*64), 25.6 MB

  // ---- CSR build (deterministic two-pass counting sort) + dis
  k_zero  <<<(NCH * NBUK + 255) / 256, 256, 0, stream>>>(H, NCH * NBUK);
  k_chist <<<NCH, 256, 0, stream>>>(ei, H);
  k_csum  <<<(NBUK + 255) / 256, 256, 0, stream>>>(H, tot);
  k_bscan <<<1, 1024, 0, stream>>>(tot, boff);
  k_scat  <<<NCH, 1024, 0, stream>>>(ei, H, boff, se);
  k_blocal<<<NBUK, 256, 0, stream>>>(se, boff, rowptr, dis, csr_src);

  // ---- layer 1: 64 -> 64, tanh
  k_gemm64_h<<<1250, 256, 0, stream>>>(x, W1, dis, Ah);
  k_agg64v<true><<<(NN + 15) / 16, 256, 0, stream>>>(rowptr, csr_src, Ah, dis, b1, B);

  // ---- layer 2: 64 -> 32, tanh
  k_gemm32_h<<<1250, 256, 0, stream>>>(B, W2, dis, Ah);
  k_agg32v<true><<<(NN + 15) / 16, 256, 0, stream>>>(rowptr, csr_src, Ah, dis, b2, B);

  // ---- layer 3: 32 -> 1 (no activation) -> d_out
  k_gemm_scale<32, 1><<<(NN + 255) / 256, 256, 0, stream>>>(B, W3, dis, Af);
  k_agg1<<<(NN + 255) / 256, 256, 0, stream>>>(rowptr, csr_src, Af, dis, b3, out);
}

// Round 12
// 267.553 us; speedup vs baseline: 1.4800x; 1.0663x over previous
//
#include <hip/hip_runtime.h>
#include <hip/hip_fp16.h>
#include <math.h>

static constexpr int NN = 100000;   // nodes
static constexpr int NE = 1600000;  // edges
static constexpr int BUCK_SH = 5;   // 32 nodes per bucket
static constexpr int NBUK = NN >> BUCK_SH;   // 3125 (exact)
static constexpr int NCH = 256;              // chunks (one scat block each)
static constexpr int CH = NE / NCH;          // 6250 edges per chunk (exact)

// pass 1: per-chunk bucket histogram H[chunk][bucket], LDS-staged (full overwrite)
__global__ __launch_bounds__(256)
void k_chist(const int* __restrict__ ei, int* __restrict__ H) {
  __shared__ int h[NBUK];
  for (int i = threadIdx.x; i < NBUK; i += 256) h[i] = 0;
  __syncthreads();
  int chunk = blockIdx.x;
  int start = chunk * CH;
  for (int e = start + threadIdx.x; e < start + CH; e += 256)
    atomicAdd(&h[ei[NE + e] >> BUCK_SH], 1);
  __syncthreads();
  int* Hc = H + chunk * NBUK;
  for (int i = threadIdx.x; i < NBUK; i += 256) Hc[i] = h[i];
}

// pass 2: in-place exclusive prefix over chunks per bucket; totals -> tot
__global__ void k_csum(int* __restrict__ H, int* __restrict__ tot) {
  int b = blockIdx.x * blockDim.x + threadIdx.x;
  if (b >= NBUK) return;
  int acc = 0;
#pragma unroll 4
  for (int c = 0; c < NCH; ++c) {
    int v = H[c * NBUK + b];
    H[c * NBUK + b] = acc;
    acc += v;
  }
  tot[b] = acc;
}

// single-block scan of bucket totals -> boff (exclusive), boff[NBUK]=NE
__global__ __launch_bounds__(1024)
void k_bscan(const int* __restrict__ tot, int* __restrict__ boff) {
  __shared__ int buf[1024];
  __shared__ int s_carry;
  int tid = threadIdx.x;
  if (tid == 0) s_carry = 0;
  __syncthreads();
  for (int base = 0; base < NBUK; base += 1024) {
    int i = base + tid;
    int v = (i < NBUK) ? tot[i] : 0;
    buf[tid] = v;
    __syncthreads();
#pragma unroll
    for (int off = 1; off < 1024; off <<= 1) {
      int t = (tid >= off) ? buf[tid - off] : 0;
      __syncthreads();
      buf[tid] += t;
      __syncthreads();
    }
    int excl = buf[tid] - v;
    int carry = s_carry;
    if (i < NBUK) boff[i] = carry + excl;
    __syncthreads();
    if (tid == 1023) s_carry = carry + buf[1023];
    __syncthreads();
  }
  if (tid == 0) boff[NBUK] = s_carry;   // == NE
}

// pass 3: one block per chunk; LDS cursors; write packed (dstLow5,src) u32
__global__ __launch_bounds__(1024)
void k_scat(const int* __restrict__ ei, const int* __restrict__ H,
            const int* __restrict__ boff, unsigned* __restrict__ se) {
  __shared__ int cur[NBUK];
  int chunk = blockIdx.x;
  const int* Hc = H + chunk * NBUK;
  for (int i = threadIdx.x; i < NBUK; i += 1024) cur[i] = boff[i] + Hc[i];
  __syncthreads();
  int start = chunk * CH;
  for (int e = start + threadIdx.x; e < start + CH; e += 1024) {
    int src = ei[e], dst = ei[NE + e];
    int pos = atomicAdd(&cur[dst >> BUCK_SH], 1);
    se[pos] = ((unsigned)(dst & 31) << 20) | (unsigned)src;   // src < 2^17
  }
}

// one block per bucket: local counting sort -> rowptr, dis, csr_src
__global__ __launch_bounds__(256)
void k_blocal(const unsigned* __restrict__ se, const int* __restrict__ boff,
              int* __restrict__ rowptr, float* __restrict__ dis, int* __restrict__ csr_src) {
  int b = blockIdx.x;
  int base = boff[b], end = boff[b + 1];
  __shared__ int cnt[32], off[32];
  int tid = threadIdx.x;
  if (tid < 32) cnt[tid] = 0;
  __syncthreads();
  for (int k = base + tid; k < end; k += 256)
    atomicAdd(&cnt[se[k] >> 20], 1);
  __syncthreads();
  if (tid == 0) {
    int acc = 0;
#pragma unroll
    for (int i = 0; i < 32; ++i) { off[i] = acc; acc += cnt[i]; }
  }
  __syncthreads();
  if (tid < 32) {
    int node = (b << BUCK_SH) + tid;
    rowptr[node] = base + off[tid];
    dis[node] = rsqrtf(1.0f + (float)cnt[tid]);
    cnt[tid] = 0;                       // reuse as cursor
  }
  if (b == 0 && tid == 64) rowptr[NN] = NE;
  __syncthreads();
  for (int k = base + tid; k < end; k += 256) {
    unsigned e = se[k];
    int dl = e >> 20;
    int pos = base + off[dl] + atomicAdd(&cnt[dl], 1);
    csr_src[pos] = (int)(e & 0xFFFFFu);
  }
}

// GEMM 64->64 (fp32 in), fp16 out. W-column in registers; rows staged in LDS.
__global__ __launch_bounds__(256)
void k_gemm64_h(const float* __restrict__ in, const float* __restrict__ W,
                const float* __restrict__ dis, __half* __restrict__ g) {
  __shared__ float rows[16 * 64];      // 4 KB
  int c = threadIdx.x & 63;
  int wid = threadIdx.x >> 6;          // 4 waves/block
  float Wc[64];
#pragma unroll
  for (int k = 0; k < 64; ++k) Wc[k] = W[k * 64 + c];
  int tiles = NN / 16;                 // 6250
  for (int t = blockIdx.x; t < tiles; t += gridDim.x) {
    int row0 = t * 16;
    __syncthreads();
    ((float4*)rows)[threadIdx.x] = ((const float4*)(in + (size_t)row0 * 64))[threadIdx.x];
    __syncthreads();
#pragma unroll
    for (int r = 0; r < 4; ++r) {
      const float* rp = rows + (wid * 4 + r) * 64;
      float acc = 0.f;
#pragma unroll
      for (int kc = 0; kc < 64; kc += 4) {
        float4 v = *(const float4*)(rp + kc);   // broadcast ds_read_b128
        acc = fmaf(v.x, Wc[kc + 0], acc);
        acc = fmaf(v.y, Wc[kc + 1], acc);
        acc = fmaf(v.z, Wc[kc + 2], acc);
        acc = fmaf(v.w, Wc[kc + 3], acc);
      }
      int row = row0 + wid * 4 + r;
      g[row * 64 + c] = __float2half(acc * dis[row]);
    }
  }
}

// GEMM 64->32 (fp16 in), fp16 out. lane&31 = column, lane>>5 = K-half.
__global__ __launch_bounds__(256)
void k_gemm32_h(const __half* __restrict__ inh, const float* __restrict__ W,
                const float* __restrict__ dis, __half* __restrict__ g) {
  __shared__ float rows[16 * 64];      // 4 KB (fp32 after unpack)
  int lane = threadIdx.x & 63;
  int c = lane & 31;
  int ksub = lane >> 5;                // 0 or 1
  int wid = threadIdx.x >> 6;
  float Wc[32];
#pragma unroll
  for (int k = 0; k < 32; ++k) Wc[k] = W[(ksub * 32 + k) * 32 + c];
  int tiles = NN / 16;
  for (int t = blockIdx.x; t < tiles; t += gridDim.x) {
    int row0 = t * 16;
    __syncthreads();
    {
      float2 raw = ((const float2*)(inh + (size_t)row0 * 64))[threadIdx.x]; // 8 B = 4 halves
      __half2* hp = (__half2*)&raw;
      float2 f01 = __half22float2(hp[0]);
      float2 f23 = __half22float2(hp[1]);
      float4 w = {f01.x, f01.y, f23.x, f23.y};
      ((float4*)rows)[threadIdx.x] = w;
    }
    __syncthreads();
#pragma unroll
    for (int r = 0; r < 4; ++r) {
      const float* rp = rows + (wid * 4 + r) * 64 + ksub * 32;
      float acc = 0.f;
#pragma unroll
      for (int kc = 0; kc < 32; kc += 4) {
        float4 v = *(const float4*)(rp + kc);
        acc = fmaf(v.x, Wc[kc + 0], acc);
        acc = fmaf(v.y, Wc[kc + 1], acc);
        acc = fmaf(v.z, Wc[kc + 2], acc);
        acc = fmaf(v.w, Wc[kc + 3], acc);
      }
      acc += __shfl_down(acc, 32);     // combine K-halves
      int row = row0 + wid * 4 + r;
      if (ksub == 0) g[row * 32 + c] = __float2half(acc * dis[row]);
    }
  }
}

// fp32 GEMM for the tiny last layer (32 -> 1)
template<int K, int C>
__global__ void k_gemm_scale(const float* __restrict__ in, const float* __restrict__ W,
                             const float* __restrict__ dis, float* __restrict__ g) {
  __shared__ float Ws[K * C];
  for (int t = threadIdx.x; t < K * C; t += blockDim.x) Ws[t] = W[t];
  __syncthreads();
  constexpr int R = 256 / (C > 256 ? 256 : C);
  int t = threadIdx.x;
  int rl = t / C, c = t % C;
  int row = blockIdx.x * R + rl;
  if (row >= NN) return;
  const float* inr = in + row * K;
  float acc = 0.f;
#pragma unroll
  for (int k = 0; k < K; ++k) acc += inr[k] * Ws[k * C + c];
  g[row * C + c] = acc * dis[row];
}

__device__ __forceinline__ void unpack_add4(float2 r, float4& acc) {
  __half2 h01 = *(__half2*)&r.x;
  __half2 h23 = *(__half2*)&r.y;
  float2 f01 = __half22float2(h01);
  float2 f23 = __half22float2(h23);
  acc.x += f01.x; acc.y += f01.y; acc.z += f23.x; acc.w += f23.y;
}

// fast tanh: 1 - 2/(e^{2x}+1); saturates correctly
__device__ __forceinline__ float fast_tanh(float x) {
  float e = __expf(2.0f * x);
  return 1.0f - 2.0f / (e + 1.0f);
}

// C=64 agg: 4 nodes per wave, 16 lanes/node, float2 fp16 loads, 4-deep MLP.
// Output fp16 (post-tanh h1).
__global__ __launch_bounds__(256)
void k_agg64v(const int* __restrict__ rowptr, const int* __restrict__ csr_src,
              const __half* __restrict__ g, const float* __restrict__ dis,
              const float* __restrict__ b, __half* __restrict__ outh) {
  int lane = threadIdx.x & 63;
  int grp = lane >> 4;                 // node slot within wave
  int cl = lane & 15;                  // channel quad
  int node = blockIdx.x * 16 + (threadIdx.x >> 6) * 4 + grp;
  if (node >= NN) return;
  const char* base = (const char*)g;
  float4 a0 = {0.f, 0.f, 0.f, 0.f}, a1 = {0.f, 0.f, 0.f, 0.f};
  float4 a2 = {0.f, 0.f, 0.f, 0.f}, a3 = {0.f, 0.f, 0.f, 0.f};
  {                                    // self loop
    float2 r = *(const float2*)(base + (size_t)node * 128 + cl * 8);
    unpack_add4(r, a0);
  }
  int k = rowptr[node], end = rowptr[node + 1];
  for (; k + 4 <= end; k += 4) {
    int s0 = csr_src[k], s1 = csr_src[k + 1], s2 = csr_src[k + 2], s3 = csr_src[k + 3];
    float2 r0 = *(const float2*)(base + (size_t)s0 * 128 + cl * 8);
    float2 r1 = *(const float2*)(base + (size_t)s1 * 128 + cl * 8);
    float2 r2 = *(const float2*)(base + (size_t)s2 * 128 + cl * 8);
    float2 r3 = *(const float2*)(base + (size_t)s3 * 128 + cl * 8);
    unpack_add4(r0, a0); unpack_add4(r1, a1);
    unpack_add4(r2, a2); unpack_add4(r3, a3);
  }
  for (; k < end; ++k) {
    float2 r = *(const float2*)(base + (size_t)csr_src[k] * 128 + cl * 8);
    unpack_add4(r, a0);
  }
  float d = dis[node];
  float4 bb = *(const float4*)(b + cl * 4);
  float4 v;
  v.x = ((a0.x + a1.x) + (a2.x + a3.x)) * d + bb.x;
  v.y = ((a0.y + a1.y) + (a2.y + a3.y)) * d + bb.y;
  v.z = ((a0.z + a1.z) + (a2.z + a3.z)) * d + bb.z;
  v.w = ((a0.w + a1.w) + (a2.w + a3.w)) * d + bb.w;
  v.x = fast_tanh(v.x); v.y = fast_tanh(v.y);
  v.z = fast_tanh(v.z); v.w = fast_tanh(v.w);
  __half2 h01 = __floats2half2_rn(v.x, v.y);
  __half2 h23 = __floats2half2_rn(v.z, v.w);
  float2 st;
  *(__half2*)&st.x = h01;
  *(__half2*)&st.y = h23;
  *(float2*)((char*)outh + (size_t)node * 128 + cl * 8) = st;
}

// C=32 agg: 4 nodes per wave; lane cl covers channels cl*2, cl*2+1; 4-deep MLP.
// Output fp32 h2.
__global__ __launch_bounds__(256)
void k_agg32v(const int* __restrict__ rowptr, const int* __restrict__ csr_src,
              const __half* __restrict__ g, const float* __restrict__ dis,
              const float* __restrict__ b, float* __restrict__ out) {
  int lane = threadIdx.x & 63;
  int grp = lane >> 4;
  int cl = lane & 15;
  int node = blockIdx.x * 16 + (threadIdx.x >> 6) * 4 + grp;
  if (node >= NN) return;
  const char* base = (const char*)g;
  float ax0 = 0.f, ay0 = 0.f, ax1 = 0.f, ay1 = 0.f;
  float ax2 = 0.f, ay2 = 0.f, ax3 = 0.f, ay3 = 0.f;
  {                                    // self loop
    unsigned u = *(const unsigned*)(base + (size_t)node * 64 + cl * 4);
    float2 f = __half22float2(*(__half2*)&u);
    ax0 += f.x; ay0 += f.y;
  }
  int k = rowptr[node], end = rowptr[node + 1];
  for (; k + 4 <= end; k += 4) {
    int s0 = csr_src[k], s1 = csr_src[k + 1], s2 = csr_src[k + 2], s3 = csr_src[k + 3];
    unsigned u0 = *(const unsigned*)(base + (size_t)s0 * 64 + cl * 4);
    unsigned u1 = *(const unsigned*)(base + (size_t)s1 * 64 + cl * 4);
    unsigned u2 = *(const unsigned*)(base + (size_t)s2 * 64 + cl * 4);
    unsigned u3 = *(const unsigned*)(base + (size_t)s3 * 64 + cl * 4);
    float2 f0 = __half22float2(*(__half2*)&u0);
    float2 f1 = __half22float2(*(__half2*)&u1);
    float2 f2 = __half22float2(*(__half2*)&u2);
    float2 f3 = __half22float2(*(__half2*)&u3);
    ax0 += f0.x; ay0 += f0.y; ax1 += f1.x; ay1 += f1.y;
    ax2 += f2.x; ay2 += f2.y; ax3 += f3.x; ay3 += f3.y;
  }
  for (; k < end; ++k) {
    unsigned u = *(const unsigned*)(base + (size_t)csr_src[k] * 64 + cl * 4);
    float2 f = __half22float2(*(__half2*)&u);
    ax0 += f.x; ay0 += f.y;
  }
  float d = dis[node];
  float2 bb = *(const float2*)(b + cl * 2);
  float vx = ((ax0 + ax1) + (ax2 + ax3)) * d + bb.x;
  float vy = ((ay0 + ay1) + (ay2 + ay3)) * d + bb.y;
  vx = fast_tanh(vx); vy = fast_tanh(vy);
  float2 v = {vx, vy};
  *(float2*)(out + (size_t)node * 32 + cl * 2) = v;
}

// C=1: thread per node, fp32 (tiny).
__global__ void k_agg1(const int* __restrict__ rowptr, const int* __restrict__ csr_src,
                       const float* __restrict__ g, const float* __restrict__ dis,
                       const float* __restrict__ b, float* __restrict__ out) {
  int node = blockIdx.x * blockDim.x + threadIdx.x;
  if (node >= NN) return;
  float a0 = g[node], a1 = 0.f, a2 = 0.f, a3 = 0.f;
  int beg = rowptr[node], end = rowptr[node + 1];
  int k = beg;
  for (; k + 4 <= end; k += 4) {
    float m0 = g[csr_src[k]], m1 = g[csr_src[k + 1]];
    float m2 = g[csr_src[k + 2]], m3 = g[csr_src[k + 3]];
    a0 += m0; a1 += m1; a2 += m2; a3 += m3;
  }
  for (; k < end; ++k) a0 += g[csr_src[k]];
  out[node] = ((a0 + a1) + (a2 + a3)) * dis[node] + b[0];
}

extern "C" void kernel_launch(void* const* d_in, const int* in_sizes, int n_in,
                              void* d_out, int out_size, void* d_ws, size_t ws_size,
                              hipStream_t stream) {
  const float* x  = (const float*)d_in[0];
  const int*   ei = (const int*)d_in[1];
  const float* W1 = (const float*)d_in[2];
  const float* b1 = (const float*)d_in[3];
  const float* W2 = (const float*)d_in[4];
  const float* b2 = (const float*)d_in[5];
  const float* W3 = (const float*)d_in[6];
  const float* b3 = (const float*)d_in[7];
  float* out = (float*)d_out;

  char* ws = (char*)d_ws;
  int*      H       = (int*)ws;      ws += (size_t)NCH * NBUK * 4;          // 3.2 MB
  int*      tot     = (int*)ws;      ws += ((NBUK + 255)/256)*256 * 4;
  int*      boff    = (int*)ws;      ws += ((NBUK + 1 + 255)/256)*256 * 4;
  unsigned* se      = (unsigned*)ws; ws += (size_t)NE * 4;                  // 6.4 MB
  int*      rowptr  = (int*)ws;      ws += ((NN + 1 + 255)/256)*256 * 4;
  int*      csr_src = (int*)ws;      ws += (size_t)NE * 4;                  // 6.4 MB
  float*    dis     = (float*)ws;    ws += ((NN + 255)/256)*256 * 4;
  __half*   Ah      = (__half*)ws;   ws += (size_t)NN * 64 * 2;             // 12.8 MB msgs
  __half*   B1h     = (__half*)ws;   ws += (size_t)NN * 64 * 2;             // 12.8 MB h1
  float*    Af      = (float*)ws;    ws += (size_t)NN * 4;
  float*    B2      = (float*)ws;    // fp32 h2 (N*32), 12.8 MB

  // ---- CSR build (deterministic two-pass counting sort) + dis
  k_chist <<<NCH, 256, 0, stream>>>(ei, H);
  k_csum  <<<(NBUK + 255) / 256, 256, 0, stream>>>(H, tot);
  k_bscan <<<1, 1024, 0, stream>>>(tot, boff);
  k_scat  <<<NCH, 1024, 0, stream>>>(ei, H, boff, se);
  k_blocal<<<NBUK, 256, 0, stream>>>(se, boff, rowptr, dis, csr_src);

  // ---- layer 1: 64 -> 64, tanh (h1 in fp16)
  k_gemm64_h<<<1250, 256, 0, stream>>>(x, W1, dis, Ah);
  k_agg64v<<<(NN + 15) / 16, 256, 0, stream>>>(rowptr, csr_src, Ah, dis, b1, B1h);

  // ---- layer 2: 64 -> 32, tanh
  k_gemm32_h<<<1250, 256, 0, stream>>>(B1h, W2, dis, Ah);
  k_agg32v<<<(NN + 15) / 16, 256, 0, stream>>>(rowptr, csr_src, Ah, dis, b2, B2);

  // ---- layer 3: 32 -> 1 (no activation) -> d_out
  k_gemm_scale<32, 1><<<(NN + 255) / 256, 256, 0, stream>>>(B2, W3, dis, Af);
  k_agg1<<<(NN + 255) / 256, 256, 0, stream>>>(rowptr, csr_src, Af, dis, b3, out);
}

// Round 13
// 260.544 us; speedup vs baseline: 1.5198x; 1.0269x over previous
//
#include <hip/hip_runtime.h>
#include <hip/hip_fp16.h>
#include <math.h>

static constexpr int NN = 100000;   // nodes
static constexpr int NE = 1600000;  // edges
static constexpr int BUCK_SH = 5;   // 32 nodes per bucket
static constexpr int NBUK = NN >> BUCK_SH;   // 3125 (exact)
static constexpr int NCH = 256;              // chunks (one scat block each)
static constexpr int CH = NE / NCH;          // 6250 edges per chunk (exact)

// pass 1: per-chunk bucket histogram H[chunk][bucket], LDS-staged (full overwrite)
__global__ __launch_bounds__(256)
void k_chist(const int* __restrict__ ei, int* __restrict__ H) {
  __shared__ int h[NBUK];
  for (int i = threadIdx.x; i < NBUK; i += 256) h[i] = 0;
  __syncthreads();
  int chunk = blockIdx.x;
  int start = chunk * CH;
  for (int e = start + threadIdx.x; e < start + CH; e += 256)
    atomicAdd(&h[ei[NE + e] >> BUCK_SH], 1);
  __syncthreads();
  int* Hc = H + chunk * NBUK;
  for (int i = threadIdx.x; i < NBUK; i += 256) Hc[i] = h[i];
}

// pass 2: in-place exclusive prefix over chunks per bucket; totals -> tot
__global__ void k_csum(int* __restrict__ H, int* __restrict__ tot) {
  int b = blockIdx.x * blockDim.x + threadIdx.x;
  if (b >= NBUK) return;
  int acc = 0;
#pragma unroll 4
  for (int c = 0; c < NCH; ++c) {
    int v = H[c * NBUK + b];
    H[c * NBUK + b] = acc;
    acc += v;
  }
  tot[b] = acc;
}

// single-block scan of bucket totals -> boff (exclusive), boff[NBUK]=NE
__global__ __launch_bounds__(1024)
void k_bscan(const int* __restrict__ tot, int* __restrict__ boff) {
  __shared__ int buf[1024];
  __shared__ int s_carry;
  int tid = threadIdx.x;
  if (tid == 0) s_carry = 0;
  __syncthreads();
  for (int base = 0; base < NBUK; base += 1024) {
    int i = base + tid;
    int v = (i < NBUK) ? tot[i] : 0;
    buf[tid] = v;
    __syncthreads();
#pragma unroll
    for (int off = 1; off < 1024; off <<= 1) {
      int t = (tid >= off) ? buf[tid - off] : 0;
      __syncthreads();
      buf[tid] += t;
      __syncthreads();
    }
    int excl = buf[tid] - v;
    int carry = s_carry;
    if (i < NBUK) boff[i] = carry + excl;
    __syncthreads();
    if (tid == 1023) s_carry = carry + buf[1023];
    __syncthreads();
  }
  if (tid == 0) boff[NBUK] = s_carry;   // == NE
}

// pass 3: one block per chunk; LDS cursors; write packed (dstLow5,src) u32
__global__ __launch_bounds__(1024)
void k_scat(const int* __restrict__ ei, const int* __restrict__ H,
            const int* __restrict__ boff, unsigned* __restrict__ se) {
  __shared__ int cur[NBUK];
  int chunk = blockIdx.x;
  const int* Hc = H + chunk * NBUK;
  for (int i = threadIdx.x; i < NBUK; i += 1024) cur[i] = boff[i] + Hc[i];
  __syncthreads();
  int start = chunk * CH;
  for (int e = start + threadIdx.x; e < start + CH; e += 1024) {
    int src = ei[e], dst = ei[NE + e];
    int pos = atomicAdd(&cur[dst >> BUCK_SH], 1);
    se[pos] = ((unsigned)(dst & 31) << 20) | (unsigned)src;   // src < 2^17
  }
}

// one block per bucket: local counting sort -> rowptr, dis, csr_src
__global__ __launch_bounds__(256)
void k_blocal(const unsigned* __restrict__ se, const int* __restrict__ boff,
              int* __restrict__ rowptr, float* __restrict__ dis, int* __restrict__ csr_src) {
  int b = blockIdx.x;
  int base = boff[b], end = boff[b + 1];
  __shared__ int cnt[32], off[32];
  int tid = threadIdx.x;
  if (tid < 32) cnt[tid] = 0;
  __syncthreads();
  for (int k = base + tid; k < end; k += 256)
    atomicAdd(&cnt[se[k] >> 20], 1);
  __syncthreads();
  if (tid == 0) {
    int acc = 0;
#pragma unroll
    for (int i = 0; i < 32; ++i) { off[i] = acc; acc += cnt[i]; }
  }
  __syncthreads();
  if (tid < 32) {
    int node = (b << BUCK_SH) + tid;
    rowptr[node] = base + off[tid];
    dis[node] = rsqrtf(1.0f + (float)cnt[tid]);
    cnt[tid] = 0;                       // reuse as cursor
  }
  if (b == 0 && tid == 64) rowptr[NN] = NE;
  __syncthreads();
  for (int k = base + tid; k < end; k += 256) {
    unsigned e = se[k];
    int dl = e >> 20;
    int pos = base + off[dl] + atomicAdd(&cnt[dl], 1);
    csr_src[pos] = (int)(e & 0xFFFFFu);
  }
}

// GEMM 64->64 (fp32 in), fp16 out. W-column in registers; rows staged in LDS.
__global__ __launch_bounds__(256)
void k_gemm64_h(const float* __restrict__ in, const float* __restrict__ W,
                const float* __restrict__ dis, __half* __restrict__ g) {
  __shared__ float rows[16 * 64];      // 4 KB
  int c = threadIdx.x & 63;
  int wid = threadIdx.x >> 6;          // 4 waves/block
  float Wc[64];
#pragma unroll
  for (int k = 0; k < 64; ++k) Wc[k] = W[k * 64 + c];
  int tiles = NN / 16;                 // 6250
  for (int t = blockIdx.x; t < tiles; t += gridDim.x) {
    int row0 = t * 16;
    __syncthreads();
    ((float4*)rows)[threadIdx.x] = ((const float4*)(in + (size_t)row0 * 64))[threadIdx.x];
    __syncthreads();
#pragma unroll
    for (int r = 0; r < 4; ++r) {
      const float* rp = rows + (wid * 4 + r) * 64;
      float acc = 0.f;
#pragma unroll
      for (int kc = 0; kc < 64; kc += 4) {
        float4 v = *(const float4*)(rp + kc);   // broadcast ds_read_b128
        acc = fmaf(v.x, Wc[kc + 0], acc);
        acc = fmaf(v.y, Wc[kc + 1], acc);
        acc = fmaf(v.z, Wc[kc + 2], acc);
        acc = fmaf(v.w, Wc[kc + 3], acc);
      }
      int row = row0 + wid * 4 + r;
      g[row * 64 + c] = __float2half(acc * dis[row]);
    }
  }
}

// GEMM 64->32 (fp16 in), fp16 out. lane&31 = column, lane>>5 = K-half.
__global__ __launch_bounds__(256)
void k_gemm32_h(const __half* __restrict__ inh, const float* __restrict__ W,
                const float* __restrict__ dis, __half* __restrict__ g) {
  __shared__ float rows[16 * 64];      // 4 KB (fp32 after unpack)
  int lane = threadIdx.x & 63;
  int c = lane & 31;
  int ksub = lane >> 5;                // 0 or 1
  int wid = threadIdx.x >> 6;
  float Wc[32];
#pragma unroll
  for (int k = 0; k < 32; ++k) Wc[k] = W[(ksub * 32 + k) * 32 + c];
  int tiles = NN / 16;
  for (int t = blockIdx.x; t < tiles; t += gridDim.x) {
    int row0 = t * 16;
    __syncthreads();
    {
      float2 raw = ((const float2*)(inh + (size_t)row0 * 64))[threadIdx.x]; // 8 B = 4 halves
      __half2* hp = (__half2*)&raw;
      float2 f01 = __half22float2(hp[0]);
      float2 f23 = __half22float2(hp[1]);
      float4 w = {f01.x, f01.y, f23.x, f23.y};
      ((float4*)rows)[threadIdx.x] = w;
    }
    __syncthreads();
#pragma unroll
    for (int r = 0; r < 4; ++r) {
      const float* rp = rows + (wid * 4 + r) * 64 + ksub * 32;
      float acc = 0.f;
#pragma unroll
      for (int kc = 0; kc < 32; kc += 4) {
        float4 v = *(const float4*)(rp + kc);
        acc = fmaf(v.x, Wc[kc + 0], acc);
        acc = fmaf(v.y, Wc[kc + 1], acc);
        acc = fmaf(v.z, Wc[kc + 2], acc);
        acc = fmaf(v.w, Wc[kc + 3], acc);
      }
      acc += __shfl_down(acc, 32);     // combine K-halves
      int row = row0 + wid * 4 + r;
      if (ksub == 0) g[row * 32 + c] = __float2half(acc * dis[row]);
    }
  }
}

// fast tanh: 1 - 2/(e^{2x}+1); saturates correctly
__device__ __forceinline__ float fast_tanh(float x) {
  float e = __expf(2.0f * x);
  return 1.0f - 2.0f / (e + 1.0f);
}

// unpack 8 fp16 (in a float4) and add into two float4 accumulators
__device__ __forceinline__ void upadd8(float4 r, float4& lo, float4& hi) {
  __half2* h = (__half2*)&r;
  float2 f0 = __half22float2(h[0]);
  float2 f1 = __half22float2(h[1]);
  float2 f2 = __half22float2(h[2]);
  float2 f3 = __half22float2(h[3]);
  lo.x += f0.x; lo.y += f0.y; lo.z += f1.x; lo.w += f1.y;
  hi.x += f2.x; hi.y += f2.y; hi.z += f3.x; hi.w += f3.y;
}

// C=64 agg: 8 nodes per wave, 8 lanes/node; each lane loads float4 = 8 fp16
// channels, so ONE group-load covers the full 128 B row. 4-deep MLP.
// Output fp16 h1.
__global__ __launch_bounds__(256)
void k_agg64v(const int* __restrict__ rowptr, const int* __restrict__ csr_src,
              const __half* __restrict__ g, const float* __restrict__ dis,
              const float* __restrict__ b, __half* __restrict__ outh) {
  int lane = threadIdx.x & 63;
  int grp = lane >> 3;                 // node slot 0..7
  int cl = lane & 7;                   // channel octet: ch cl*8..cl*8+7
  int node = blockIdx.x * 32 + (threadIdx.x >> 6) * 8 + grp;
  if (node >= NN) return;
  const char* base = (const char*)g;
  float4 l0 = {0,0,0,0}, h0 = {0,0,0,0}, l1 = {0,0,0,0}, h1 = {0,0,0,0};
  float4 l2 = {0,0,0,0}, h2 = {0,0,0,0}, l3 = {0,0,0,0}, h3 = {0,0,0,0};
  {                                    // self loop
    float4 r = *(const float4*)(base + (size_t)node * 128 + cl * 16);
    upadd8(r, l0, h0);
  }
  int k = rowptr[node], end = rowptr[node + 1];
  for (; k + 4 <= end; k += 4) {
    int s0 = csr_src[k], s1 = csr_src[k + 1], s2 = csr_src[k + 2], s3 = csr_src[k + 3];
    float4 r0 = *(const float4*)(base + (size_t)s0 * 128 + cl * 16);
    float4 r1 = *(const float4*)(base + (size_t)s1 * 128 + cl * 16);
    float4 r2 = *(const float4*)(base + (size_t)s2 * 128 + cl * 16);
    float4 r3 = *(const float4*)(base + (size_t)s3 * 128 + cl * 16);
    upadd8(r0, l0, h0); upadd8(r1, l1, h1);
    upadd8(r2, l2, h2); upadd8(r3, l3, h3);
  }
  for (; k < end; ++k) {
    float4 r = *(const float4*)(base + (size_t)csr_src[k] * 128 + cl * 16);
    upadd8(r, l0, h0);
  }
  float d = dis[node];
  float4 blo = *(const float4*)(b + cl * 8);
  float4 bhi = *(const float4*)(b + cl * 8 + 4);
  float4 vl, vh;
  vl.x = ((l0.x + l1.x) + (l2.x + l3.x)) * d + blo.x;
  vl.y = ((l0.y + l1.y) + (l2.y + l3.y)) * d + blo.y;
  vl.z = ((l0.z + l1.z) + (l2.z + l3.z)) * d + blo.z;
  vl.w = ((l0.w + l1.w) + (l2.w + l3.w)) * d + blo.w;
  vh.x = ((h0.x + h1.x) + (h2.x + h3.x)) * d + bhi.x;
  vh.y = ((h0.y + h1.y) + (h2.y + h3.y)) * d + bhi.y;
  vh.z = ((h0.z + h1.z) + (h2.z + h3.z)) * d + bhi.z;
  vh.w = ((h0.w + h1.w) + (h2.w + h3.w)) * d + bhi.w;
  vl.x = fast_tanh(vl.x); vl.y = fast_tanh(vl.y);
  vl.z = fast_tanh(vl.z); vl.w = fast_tanh(vl.w);
  vh.x = fast_tanh(vh.x); vh.y = fast_tanh(vh.y);
  vh.z = fast_tanh(vh.z); vh.w = fast_tanh(vh.w);
  float4 st;
  ((__half2*)&st)[0] = __floats2half2_rn(vl.x, vl.y);
  ((__half2*)&st)[1] = __floats2half2_rn(vl.z, vl.w);
  ((__half2*)&st)[2] = __floats2half2_rn(vh.x, vh.y);
  ((__half2*)&st)[3] = __floats2half2_rn(vh.z, vh.w);
  *(float4*)((char*)outh + (size_t)node * 128 + cl * 16) = st;
}

// C=32 agg fused with layer-3 GEMM: 8 nodes per wave, 8 lanes/node; each lane
// loads float2 = 4 fp16 channels (group covers full 64 B row). 4-deep MLP.
// Epilogue: tanh -> h2 (4 ch/lane), dot with W3 segment, shfl-reduce over the
// 8-lane group, lane 0 stores Af[node] = (h2 . W3) * dis[node].
__global__ __launch_bounds__(256)
void k_agg32v(const int* __restrict__ rowptr, const int* __restrict__ csr_src,
              const __half* __restrict__ g, const float* __restrict__ dis,
              const float* __restrict__ b, const float* __restrict__ W3,
              float* __restrict__ Af) {
  int lane = threadIdx.x & 63;
  int grp = lane >> 3;                 // node slot 0..7
  int cl = lane & 7;                   // channel quad: ch cl*4..cl*4+3
  int node = blockIdx.x * 32 + (threadIdx.x >> 6) * 8 + grp;
  if (node >= NN) return;
  const char* base = (const char*)g;
  float4 a0 = {0,0,0,0}, a1 = {0,0,0,0}, a2 = {0,0,0,0}, a3 = {0,0,0,0};
  {                                    // self loop
    float2 r = *(const float2*)(base + (size_t)node * 64 + cl * 8);
    __half2* h = (__half2*)&r;
    float2 f0 = __half22float2(h[0]), f1 = __half22float2(h[1]);
    a0.x += f0.x; a0.y += f0.y; a0.z += f1.x; a0.w += f1.y;
  }
  int k = rowptr[node], end = rowptr[node + 1];
  for (; k + 4 <= end; k += 4) {
    int s0 = csr_src[k], s1 = csr_src[k + 1], s2 = csr_src[k + 2], s3 = csr_src[k + 3];
    float2 r0 = *(const float2*)(base + (size_t)s0 * 64 + cl * 8);
    float2 r1 = *(const float2*)(base + (size_t)s1 * 64 + cl * 8);
    float2 r2 = *(const float2*)(base + (size_t)s2 * 64 + cl * 8);
    float2 r3 = *(const float2*)(base + (size_t)s3 * 64 + cl * 8);
    __half2* h0 = (__half2*)&r0; __half2* h1 = (__half2*)&r1;
    __half2* h2 = (__half2*)&r2; __half2* h3 = (__half2*)&r3;
    float2 f;
    f = __half22float2(h0[0]); a0.x += f.x; a0.y += f.y;
    f = __half22float2(h0[1]); a0.z += f.x; a0.w += f.y;
    f = __half22float2(h1[0]); a1.x += f.x; a1.y += f.y;
    f = __half22float2(h1[1]); a1.z += f.x; a1.w += f.y;
    f = __half22float2(h2[0]); a2.x += f.x; a2.y += f.y;
    f = __half22float2(h2[1]); a2.z += f.x; a2.w += f.y;
    f = __half22float2(h3[0]); a3.x += f.x; a3.y += f.y;
    f = __half22float2(h3[1]); a3.z += f.x; a3.w += f.y;
  }
  for (; k < end; ++k) {
    float2 r = *(const float2*)(base + (size_t)csr_src[k] * 64 + cl * 8);
    __half2* h = (__half2*)&r;
    float2 f0 = __half22float2(h[0]), f1 = __half22float2(h[1]);
    a0.x += f0.x; a0.y += f0.y; a0.z += f1.x; a0.w += f1.y;
  }
  float d = dis[node];
  float4 bb = *(const float4*)(b + cl * 4);
  float4 v;
  v.x = ((a0.x + a1.x) + (a2.x + a3.x)) * d + bb.x;
  v.y = ((a0.y + a1.y) + (a2.y + a3.y)) * d + bb.y;
  v.z = ((a0.z + a1.z) + (a2.z + a3.z)) * d + bb.z;
  v.w = ((a0.w + a1.w) + (a2.w + a3.w)) * d + bb.w;
  v.x = fast_tanh(v.x); v.y = fast_tanh(v.y);
  v.z = fast_tanh(v.z); v.w = fast_tanh(v.w);
  // layer-3 message: dot(h2_row, W3) * dis
  float4 w3 = *(const float4*)(W3 + cl * 4);
  float p = v.x * w3.x + v.y * w3.y + v.z * w3.z + v.w * w3.w;
  p += __shfl_xor(p, 1);
  p += __shfl_xor(p, 2);
  p += __shfl_xor(p, 4);
  if (cl == 0) Af[node] = p * d;
}

// C=1: thread per node, fp32 (tiny).
__global__ void k_agg1(const int* __restrict__ rowptr, const int* __restrict__ csr_src,
                       const float* __restrict__ g, const float* __restrict__ dis,
                       const float* __restrict__ b, float* __restrict__ out) {
  int node = blockIdx.x * blockDim.x + threadIdx.x;
  if (node >= NN) return;
  float a0 = g[node], a1 = 0.f, a2 = 0.f, a3 = 0.f;
  int beg = rowptr[node], end = rowptr[node + 1];
  int k = beg;
  for (; k + 4 <= end; k += 4) {
    float m0 = g[csr_src[k]], m1 = g[csr_src[k + 1]];
    float m2 = g[csr_src[k + 2]], m3 = g[csr_src[k + 3]];
    a0 += m0; a1 += m1; a2 += m2; a3 += m3;
  }
  for (; k < end; ++k) a0 += g[csr_src[k]];
  out[node] = ((a0 + a1) + (a2 + a3)) * dis[node] + b[0];
}

extern "C" void kernel_launch(void* const* d_in, const int* in_sizes, int n_in,
                              void* d_out, int out_size, void* d_ws, size_t ws_size,
                              hipStream_t stream) {
  const float* x  = (const float*)d_in[0];
  const int*   ei = (const int*)d_in[1];
  const float* W1 = (const float*)d_in[2];
  const float* b1 = (const float*)d_in[3];
  const float* W2 = (const float*)d_in[4];
  const float* b2 = (const float*)d_in[5];
  const float* W3 = (const float*)d_in[6];
  const float* b3 = (const float*)d_in[7];
  float* out = (float*)d_out;

  char* ws = (char*)d_ws;
  int*      H       = (int*)ws;      ws += (size_t)NCH * NBUK * 4;          // 3.2 MB
  int*      tot     = (int*)ws;      ws += ((NBUK + 255)/256)*256 * 4;
  int*      boff    = (int*)ws;      ws += ((NBUK + 1 + 255)/256)*256 * 4;
  unsigned* se      = (unsigned*)ws; ws += (size_t)NE * 4;                  // 6.4 MB
  int*      rowptr  = (int*)ws;      ws += ((NN + 1 + 255)/256)*256 * 4;
  int*      csr_src = (int*)ws;      ws += (size_t)NE * 4;                  // 6.4 MB
  float*    dis     = (float*)ws;    ws += ((NN + 255)/256)*256 * 4;
  __half*   Ah      = (__half*)ws;   ws += (size_t)NN * 64 * 2;             // 12.8 MB msgs
  __half*   B1h     = (__half*)ws;   ws += (size_t)NN * 64 * 2;             // 12.8 MB h1
  float*    Af      = (float*)ws;    ws += (size_t)NN * 4;                  // 400 KB L3 msgs

  // ---- CSR build (deterministic two-pass counting sort) + dis
  k_chist <<<NCH, 256, 0, stream>>>(ei, H);
  k_csum  <<<(NBUK + 255) / 256, 256, 0, stream>>>(H, tot);
  k_bscan <<<1, 1024, 0, stream>>>(tot, boff);
  k_scat  <<<NCH, 1024, 0, stream>>>(ei, H, boff, se);
  k_blocal<<<NBUK, 256, 0, stream>>>(se, boff, rowptr, dis, csr_src);

  // ---- layer 1: 64 -> 64, tanh (h1 in fp16)
  k_gemm64_h<<<1250, 256, 0, stream>>>(x, W1, dis, Ah);
  k_agg64v<<<(NN + 31) / 32, 256, 0, stream>>>(rowptr, csr_src, Ah, dis, b1, B1h);

  // ---- layer 2: 64 -> 32, tanh; fused layer-3 message (h2 . W3) * dis
  k_gemm32_h<<<1250, 256, 0, stream>>>(B1h, W2, dis, Ah);
  k_agg32v<<<(NN + 31) / 32, 256, 0, stream>>>(rowptr, csr_src, Ah, dis, b2, W3, Af);

  // ---- layer 3: scalar aggregation -> d_out
  k_agg1<<<(NN + 255) / 256, 256, 0, stream>>>(rowptr, csr_src, Af, dis, b3, out);
}

// Round 14
// 251.702 us; speedup vs baseline: 1.5732x; 1.0351x over previous
//
#include <hip/hip_runtime.h>
#include <hip/hip_fp16.h>
#include <math.h>

static constexpr int NN = 100000;   // nodes
static constexpr int NE = 1600000;  // edges
static constexpr int BUCK_SH = 5;   // 32 nodes per bucket
static constexpr int NBUK = NN >> BUCK_SH;   // 3125 (exact)
static constexpr int NCH = 256;              // chunks (one scat block each)
static constexpr int CH = NE / NCH;          // 6250 edges per chunk (exact)

// pass 1: per-chunk bucket histogram H[chunk][bucket], LDS-staged (full overwrite)
__global__ __launch_bounds__(256)
void k_chist(const int* __restrict__ ei, int* __restrict__ H) {
  __shared__ int h[NBUK];
  for (int i = threadIdx.x; i < NBUK; i += 256) h[i] = 0;
  __syncthreads();
  int chunk = blockIdx.x;
  int start = chunk * CH;
  for (int e = start + threadIdx.x; e < start + CH; e += 256)
    atomicAdd(&h[ei[NE + e] >> BUCK_SH], 1);
  __syncthreads();
  int* Hc = H + chunk * NBUK;
  for (int i = threadIdx.x; i < NBUK; i += 256) Hc[i] = h[i];
}

// pass 2: in-place exclusive prefix over chunks per bucket; totals -> tot
__global__ void k_csum(int* __restrict__ H, int* __restrict__ tot) {
  int b = blockIdx.x * blockDim.x + threadIdx.x;
  if (b >= NBUK) return;
  int acc = 0;
#pragma unroll 4
  for (int c = 0; c < NCH; ++c) {
    int v = H[c * NBUK + b];
    H[c * NBUK + b] = acc;
    acc += v;
  }
  tot[b] = acc;
}

// single-block scan of bucket totals -> boff (exclusive), boff[NBUK]=NE
__global__ __launch_bounds__(1024)
void k_bscan(const int* __restrict__ tot, int* __restrict__ boff) {
  __shared__ int buf[1024];
  __shared__ int s_carry;
  int tid = threadIdx.x;
  if (tid == 0) s_carry = 0;
  __syncthreads();
  for (int base = 0; base < NBUK; base += 1024) {
    int i = base + tid;
    int v = (i < NBUK) ? tot[i] : 0;
    buf[tid] = v;
    __syncthreads();
#pragma unroll
    for (int off = 1; off < 1024; off <<= 1) {
      int t = (tid >= off) ? buf[tid - off] : 0;
      __syncthreads();
      buf[tid] += t;
      __syncthreads();
    }
    int excl = buf[tid] - v;
    int carry = s_carry;
    if (i < NBUK) boff[i] = carry + excl;
    __syncthreads();
    if (tid == 1023) s_carry = carry + buf[1023];
    __syncthreads();
  }
  if (tid == 0) boff[NBUK] = s_carry;   // == NE
}

// pass 3: one block per chunk; LDS cursors; write packed (dstLow5,src) u32
__global__ __launch_bounds__(1024)
void k_scat(const int* __restrict__ ei, const int* __restrict__ H,
            const int* __restrict__ boff, unsigned* __restrict__ se) {
  __shared__ int cur[NBUK];
  int chunk = blockIdx.x;
  const int* Hc = H + chunk * NBUK;
  for (int i = threadIdx.x; i < NBUK; i += 1024) cur[i] = boff[i] + Hc[i];
  __syncthreads();
  int start = chunk * CH;
  for (int e = start + threadIdx.x; e < start + CH; e += 1024) {
    int src = ei[e], dst = ei[NE + e];
    int pos = atomicAdd(&cur[dst >> BUCK_SH], 1);
    se[pos] = ((unsigned)(dst & 31) << 20) | (unsigned)src;   // src < 2^17
  }
}

// one block per bucket: local counting sort -> rowptr, dis, csr_src
__global__ __launch_bounds__(256)
void k_blocal(const unsigned* __restrict__ se, const int* __restrict__ boff,
              int* __restrict__ rowptr, float* __restrict__ dis, int* __restrict__ csr_src) {
  int b = blockIdx.x;
  int base = boff[b], end = boff[b + 1];
  __shared__ int cnt[32], off[32];
  int tid = threadIdx.x;
  if (tid < 32) cnt[tid] = 0;
  __syncthreads();
  for (int k = base + tid; k < end; k += 256)
    atomicAdd(&cnt[se[k] >> 20], 1);
  __syncthreads();
  if (tid == 0) {
    int acc = 0;
#pragma unroll
    for (int i = 0; i < 32; ++i) { off[i] = acc; acc += cnt[i]; }
  }
  __syncthreads();
  if (tid < 32) {
    int node = (b << BUCK_SH) + tid;
    rowptr[node] = base + off[tid];
    dis[node] = rsqrtf(1.0f + (float)cnt[tid]);
    cnt[tid] = 0;                       // reuse as cursor
  }
  if (b == 0 && tid == 64) rowptr[NN] = NE;
  __syncthreads();
  for (int k = base + tid; k < end; k += 256) {
    unsigned e = se[k];
    int dl = e >> 20;
    int pos = base + off[dl] + atomicAdd(&cnt[dl], 1);
    csr_src[pos] = (int)(e & 0xFFFFFu);
  }
}

// GEMM 64->64 (fp32 in), fp16 out. W-column in registers; rows staged in LDS.
__global__ __launch_bounds__(256)
void k_gemm64_h(const float* __restrict__ in, const float* __restrict__ W,
                const float* __restrict__ dis, __half* __restrict__ g) {
  __shared__ float rows[16 * 64];      // 4 KB
  int c = threadIdx.x & 63;
  int wid = threadIdx.x >> 6;          // 4 waves/block
  float Wc[64];
#pragma unroll
  for (int k = 0; k < 64; ++k) Wc[k] = W[k * 64 + c];
  int tiles = NN / 16;                 // 6250
  for (int t = blockIdx.x; t < tiles; t += gridDim.x) {
    int row0 = t * 16;
    __syncthreads();
    ((float4*)rows)[threadIdx.x] = ((const float4*)(in + (size_t)row0 * 64))[threadIdx.x];
    __syncthreads();
#pragma unroll
    for (int r = 0; r < 4; ++r) {
      const float* rp = rows + (wid * 4 + r) * 64;
      float acc = 0.f;
#pragma unroll
      for (int kc = 0; kc < 64; kc += 4) {
        float4 v = *(const float4*)(rp + kc);   // broadcast ds_read_b128
        acc = fmaf(v.x, Wc[kc + 0], acc);
        acc = fmaf(v.y, Wc[kc + 1], acc);
        acc = fmaf(v.z, Wc[kc + 2], acc);
        acc = fmaf(v.w, Wc[kc + 3], acc);
      }
      int row = row0 + wid * 4 + r;
      g[row * 64 + c] = __float2half(acc * dis[row]);
    }
  }
}

// fast tanh: 1 - 2/(e^{2x}+1); saturates correctly
__device__ __forceinline__ float fast_tanh(float x) {
  float e = __expf(2.0f * x);
  return 1.0f - 2.0f / (e + 1.0f);
}

// unpack 8 fp16 (in a float4) and add into two float4 accumulators
__device__ __forceinline__ void upadd8(float4 r, float4& lo, float4& hi) {
  __half2* h = (__half2*)&r;
  float2 f0 = __half22float2(h[0]);
  float2 f1 = __half22float2(h[1]);
  float2 f2 = __half22float2(h[2]);
  float2 f3 = __half22float2(h[3]);
  lo.x += f0.x; lo.y += f0.y; lo.z += f1.x; lo.w += f1.y;
  hi.x += f2.x; hi.y += f2.y; hi.z += f3.x; hi.w += f3.y;
}

// Layer-1 aggregation FUSED with layer-2 GEMM.
// Gather phase: 8 nodes/wave, 8 lanes/node, float4 (=8 fp16 ch) per lane,
// 4-deep MLP. h1 = tanh(...) kept in fp32 registers (never hits HBM).
// Epilogue: wave's 8x64 h1 tile -> LDS -> gemm32 pattern (lane = col + K-half,
// W2 column in 32 VGPRs, shfl_down(32) combine) -> Ah2 = (h1@W2)*dis in fp16.
// Grid must be exactly NN/32 blocks (NN % 32 == 0) - all lanes participate.
__global__ __launch_bounds__(256)
void k_agg64f(const int* __restrict__ rowptr, const int* __restrict__ csr_src,
              const __half* __restrict__ g, const float* __restrict__ dis,
              const float* __restrict__ b, const float* __restrict__ W2,
              __half* __restrict__ g2) {
  __shared__ float tile[4][8][64];     // 8 KB: per-wave 8x64 h1 tile
  int lane = threadIdx.x & 63;
  int wid = threadIdx.x >> 6;
  int grp = lane >> 3;                 // node slot 0..7
  int cl = lane & 7;                   // channel octet: ch cl*8..cl*8+7
  int node = blockIdx.x * 32 + wid * 8 + grp;

  // W2 column segment for the epilogue (loaded early, L1/L2-resident)
  int c2 = lane & 31;                  // output column 0..31
  int ksub = lane >> 5;                // K-half 0/1
  float Wc[32];
#pragma unroll
  for (int k = 0; k < 32; ++k) Wc[k] = W2[(ksub * 32 + k) * 32 + c2];

  const char* base = (const char*)g;
  float4 l0 = {0,0,0,0}, h0 = {0,0,0,0}, l1 = {0,0,0,0}, h1 = {0,0,0,0};
  float4 l2 = {0,0,0,0}, h2 = {0,0,0,0}, l3 = {0,0,0,0}, h3 = {0,0,0,0};
  {                                    // self loop
    float4 r = *(const float4*)(base + (size_t)node * 128 + cl * 16);
    upadd8(r, l0, h0);
  }
  int k = rowptr[node], end = rowptr[node + 1];
  for (; k + 4 <= end; k += 4) {
    int s0 = csr_src[k], s1 = csr_src[k + 1], s2 = csr_src[k + 2], s3 = csr_src[k + 3];
    float4 r0 = *(const float4*)(base + (size_t)s0 * 128 + cl * 16);
    float4 r1 = *(const float4*)(base + (size_t)s1 * 128 + cl * 16);
    float4 r2 = *(const float4*)(base + (size_t)s2 * 128 + cl * 16);
    float4 r3 = *(const float4*)(base + (size_t)s3 * 128 + cl * 16);
    upadd8(r0, l0, h0); upadd8(r1, l1, h1);
    upadd8(r2, l2, h2); upadd8(r3, l3, h3);
  }
  for (; k < end; ++k) {
    float4 r = *(const float4*)(base + (size_t)csr_src[k] * 128 + cl * 16);
    upadd8(r, l0, h0);
  }
  float d = dis[node];
  float4 blo = *(const float4*)(b + cl * 8);
  float4 bhi = *(const float4*)(b + cl * 8 + 4);
  float4 vl, vh;
  vl.x = ((l0.x + l1.x) + (l2.x + l3.x)) * d + blo.x;
  vl.y = ((l0.y + l1.y) + (l2.y + l3.y)) * d + blo.y;
  vl.z = ((l0.z + l1.z) + (l2.z + l3.z)) * d + blo.z;
  vl.w = ((l0.w + l1.w) + (l2.w + l3.w)) * d + blo.w;
  vh.x = ((h0.x + h1.x) + (h2.x + h3.x)) * d + bhi.x;
  vh.y = ((h0.y + h1.y) + (h2.y + h3.y)) * d + bhi.y;
  vh.z = ((h0.z + h1.z) + (h2.z + h3.z)) * d + bhi.z;
  vh.w = ((h0.w + h1.w) + (h2.w + h3.w)) * d + bhi.w;
  vl.x = fast_tanh(vl.x); vl.y = fast_tanh(vl.y);
  vl.z = fast_tanh(vl.z); vl.w = fast_tanh(vl.w);
  vh.x = fast_tanh(vh.x); vh.y = fast_tanh(vh.y);
  vh.z = fast_tanh(vh.z); vh.w = fast_tanh(vh.w);

  // stash h1 tile in LDS (per-wave region)
  *(float4*)&tile[wid][grp][cl * 8] = vl;
  *(float4*)&tile[wid][grp][cl * 8 + 4] = vh;
  __syncthreads();

  // layer-2 GEMM on the wave's own 8 rows
  int rbase = blockIdx.x * 32 + wid * 8;
#pragma unroll
  for (int r = 0; r < 8; ++r) {
    const float* rp = &tile[wid][r][ksub * 32];
    float acc = 0.f;
#pragma unroll
    for (int kc = 0; kc < 32; kc += 4) {
      float4 v = *(const float4*)(rp + kc);   // 2-way broadcast ds_read (free)
      acc = fmaf(v.x, Wc[kc + 0], acc);
      acc = fmaf(v.y, Wc[kc + 1], acc);
      acc = fmaf(v.z, Wc[kc + 2], acc);
      acc = fmaf(v.w, Wc[kc + 3], acc);
    }
    acc += __shfl_down(acc, 32);       // combine K-halves
    int row = rbase + r;
    if (ksub == 0) g2[row * 32 + c2] = __float2half(acc * dis[row]);
  }
}

// Layer-2 aggregation fused with layer-3 GEMM: 8 nodes/wave, 8 lanes/node;
// float2 (=4 fp16 ch) per lane; 8-deep MLP. Epilogue: tanh -> h2, dot with W3
// segment, shfl-reduce over the 8-lane group, lane 0 stores (h2.W3)*dis.
__global__ __launch_bounds__(256)
void k_agg32v(const int* __restrict__ rowptr, const int* __restrict__ csr_src,
              const __half* __restrict__ g, const float* __restrict__ dis,
              const float* __restrict__ b, const float* __restrict__ W3,
              float* __restrict__ Af) {
  int lane = threadIdx.x & 63;
  int grp = lane >> 3;                 // node slot 0..7
  int cl = lane & 7;                   // channel quad: ch cl*4..cl*4+3
  int node = blockIdx.x * 32 + (threadIdx.x >> 6) * 8 + grp;
  if (node >= NN) return;
  const char* base = (const char*)g;
  float4 a0 = {0,0,0,0}, a1 = {0,0,0,0}, a2 = {0,0,0,0}, a3 = {0,0,0,0};
  {                                    // self loop
    float2 r = *(const float2*)(base + (size_t)node * 64 + cl * 8);
    __half2* h = (__half2*)&r;
    float2 f0 = __half22float2(h[0]), f1 = __half22float2(h[1]);
    a0.x += f0.x; a0.y += f0.y; a0.z += f1.x; a0.w += f1.y;
  }
  int k = rowptr[node], end = rowptr[node + 1];
  for (; k + 8 <= end; k += 8) {       // 8 gathers in flight
    float2 r0 = *(const float2*)(base + (size_t)csr_src[k + 0] * 64 + cl * 8);
    float2 r1 = *(const float2*)(base + (size_t)csr_src[k + 1] * 64 + cl * 8);
    float2 r2 = *(const float2*)(base + (size_t)csr_src[k + 2] * 64 + cl * 8);
    float2 r3 = *(const float2*)(base + (size_t)csr_src[k + 3] * 64 + cl * 8);
    float2 r4 = *(const float2*)(base + (size_t)csr_src[k + 4] * 64 + cl * 8);
    float2 r5 = *(const float2*)(base + (size_t)csr_src[k + 5] * 64 + cl * 8);
    float2 r6 = *(const float2*)(base + (size_t)csr_src[k + 6] * 64 + cl * 8);
    float2 r7 = *(const float2*)(base + (size_t)csr_src[k + 7] * 64 + cl * 8);
    __half2* h; float2 f;
    h = (__half2*)&r0; f = __half22float2(h[0]); a0.x += f.x; a0.y += f.y;
    f = __half22float2(h[1]); a0.z += f.x; a0.w += f.y;
    h = (__half2*)&r1; f = __half22float2(h[0]); a1.x += f.x; a1.y += f.y;
    f = __half22float2(h[1]); a1.z += f.x; a1.w += f.y;
    h = (__half2*)&r2; f = __half22float2(h[0]); a2.x += f.x; a2.y += f.y;
    f = __half22float2(h[1]); a2.z += f.x; a2.w += f.y;
    h = (__half2*)&r3; f = __half22float2(h[0]); a3.x += f.x; a3.y += f.y;
    f = __half22float2(h[1]); a3.z += f.x; a3.w += f.y;
    h = (__half2*)&r4; f = __half22float2(h[0]); a0.x += f.x; a0.y += f.y;
    f = __half22float2(h[1]); a0.z += f.x; a0.w += f.y;
    h = (__half2*)&r5; f = __half22float2(h[0]); a1.x += f.x; a1.y += f.y;
    f = __half22float2(h[1]); a1.z += f.x; a1.w += f.y;
    h = (__half2*)&r6; f = __half22float2(h[0]); a2.x += f.x; a2.y += f.y;
    f = __half22float2(h[1]); a2.z += f.x; a2.w += f.y;
    h = (__half2*)&r7; f = __half22float2(h[0]); a3.x += f.x; a3.y += f.y;
    f = __half22float2(h[1]); a3.z += f.x; a3.w += f.y;
  }
  for (; k + 4 <= end; k += 4) {
    float2 r0 = *(const float2*)(base + (size_t)csr_src[k + 0] * 64 + cl * 8);
    float2 r1 = *(const float2*)(base + (size_t)csr_src[k + 1] * 64 + cl * 8);
    float2 r2 = *(const float2*)(base + (size_t)csr_src[k + 2] * 64 + cl * 8);
    float2 r3 = *(const float2*)(base + (size_t)csr_src[k + 3] * 64 + cl * 8);
    __half2* h; float2 f;
    h = (__half2*)&r0; f = __half22float2(h[0]); a0.x += f.x; a0.y += f.y;
    f = __half22float2(h[1]); a0.z += f.x; a0.w += f.y;
    h = (__half2*)&r1; f = __half22float2(h[0]); a1.x += f.x; a1.y += f.y;
    f = __half22float2(h[1]); a1.z += f.x; a1.w += f.y;
    h = (__half2*)&r2; f = __half22float2(h[0]); a2.x += f.x; a2.y += f.y;
    f = __half22float2(h[1]); a2.z += f.x; a2.w += f.y;
    h = (__half2*)&r3; f = __half22float2(h[0]); a3.x += f.x; a3.y += f.y;
    f = __half22float2(h[1]); a3.z += f.x; a3.w += f.y;
  }
  for (; k < end; ++k) {
    float2 r = *(const float2*)(base + (size_t)csr_src[k] * 64 + cl * 8);
    __half2* h = (__half2*)&r;
    float2 f0 = __half22float2(h[0]), f1 = __half22float2(h[1]);
    a0.x += f0.x; a0.y += f0.y; a0.z += f1.x; a0.w += f1.y;
  }
  float d = dis[node];
  float4 bb = *(const float4*)(b + cl * 4);
  float4 v;
  v.x = ((a0.x + a1.x) + (a2.x + a3.x)) * d + bb.x;
  v.y = ((a0.y + a1.y) + (a2.y + a3.y)) * d + bb.y;
  v.z = ((a0.z + a1.z) + (a2.z + a3.z)) * d + bb.z;
  v.w = ((a0.w + a1.w) + (a2.w + a3.w)) * d + bb.w;
  v.x = fast_tanh(v.x); v.y = fast_tanh(v.y);
  v.z = fast_tanh(v.z); v.w = fast_tanh(v.w);
  // layer-3 message: dot(h2_row, W3) * dis
  float4 w3 = *(const float4*)(W3 + cl * 4);
  float p = v.x * w3.x + v.y * w3.y + v.z * w3.z + v.w * w3.w;
  p += __shfl_xor(p, 1);
  p += __shfl_xor(p, 2);
  p += __shfl_xor(p, 4);
  if (cl == 0) Af[node] = p * d;
}

// C=1: thread per node, fp32 (tiny).
__global__ void k_agg1(const int* __restrict__ rowptr, const int* __restrict__ csr_src,
                       const float* __restrict__ g, const float* __restrict__ dis,
                       const float* __restrict__ b, float* __restrict__ out) {
  int node = blockIdx.x * blockDim.x + threadIdx.x;
  if (node >= NN) return;
  float a0 = g[node], a1 = 0.f, a2 = 0.f, a3 = 0.f;
  int beg = rowptr[node], end = rowptr[node + 1];
  int k = beg;
  for (; k + 4 <= end; k += 4) {
    float m0 = g[csr_src[k]], m1 = g[csr_src[k + 1]];
    float m2 = g[csr_src[k + 2]], m3 = g[csr_src[k + 3]];
    a0 += m0; a1 += m1; a2 += m2; a3 += m3;
  }
  for (; k < end; ++k) a0 += g[csr_src[k]];
  out[node] = ((a0 + a1) + (a2 + a3)) * dis[node] + b[0];
}

extern "C" void kernel_launch(void* const* d_in, const int* in_sizes, int n_in,
                              void* d_out, int out_size, void* d_ws, size_t ws_size,
                              hipStream_t stream) {
  const float* x  = (const float*)d_in[0];
  const int*   ei = (const int*)d_in[1];
  const float* W1 = (const float*)d_in[2];
  const float* b1 = (const float*)d_in[3];
  const float* W2 = (const float*)d_in[4];
  const float* b2 = (const float*)d_in[5];
  const float* W3 = (const float*)d_in[6];
  const float* b3 = (const float*)d_in[7];
  float* out = (float*)d_out;

  char* ws = (char*)d_ws;
  int*      H       = (int*)ws;      ws += (size_t)NCH * NBUK * 4;          // 3.2 MB
  int*      tot     = (int*)ws;      ws += ((NBUK + 255)/256)*256 * 4;
  int*      boff    = (int*)ws;      ws += ((NBUK + 1 + 255)/256)*256 * 4;
  unsigned* se      = (unsigned*)ws; ws += (size_t)NE * 4;                  // 6.4 MB
  int*      rowptr  = (int*)ws;      ws += ((NN + 1 + 255)/256)*256 * 4;
  int*      csr_src = (int*)ws;      ws += (size_t)NE * 4;                  // 6.4 MB
  float*    dis     = (float*)ws;    ws += ((NN + 255)/256)*256 * 4;
  __half*   Ah      = (__half*)ws;   ws += (size_t)NN * 64 * 2;             // 12.8 MB L1 msgs
  __half*   Ah2     = (__half*)ws;   ws += (size_t)NN * 32 * 2;             // 6.4 MB L2 msgs
  float*    Af      = (float*)ws;    ws += (size_t)NN * 4;                  // 400 KB L3 msgs

  // ---- CSR build (deterministic two-pass counting sort) + dis
  k_chist <<<NCH, 256, 0, stream>>>(ei, H);
  k_csum  <<<(NBUK + 255) / 256, 256, 0, stream>>>(H, tot);
  k_bscan <<<1, 1024, 0, stream>>>(tot, boff);
  k_scat  <<<NCH, 1024, 0, stream>>>(ei, H, boff, se);
  k_blocal<<<NBUK, 256, 0, stream>>>(se, boff, rowptr, dis, csr_src);

  // ---- layer 1 GEMM: x @ W1 scaled -> fp16 messages
  k_gemm64_h<<<1250, 256, 0, stream>>>(x, W1, dis, Ah);
  // ---- layer-1 aggregation + tanh + FUSED layer-2 GEMM -> fp16 L2 messages
  k_agg64f<<<NN / 32, 256, 0, stream>>>(rowptr, csr_src, Ah, dis, b1, W2, Ah2);
  // ---- layer-2 aggregation + tanh + FUSED layer-3 GEMM -> fp32 L3 messages
  k_agg32v<<<NN / 32, 256, 0, stream>>>(rowptr, csr_src, Ah2, dis, b2, W3, Af);
  // ---- layer-3 aggregation -> d_out
  k_agg1<<<(NN + 255) / 256, 256, 0, stream>>>(rowptr, csr_src, Af, dis, b3, out);
}